// Round 1
// baseline (7473.355 us; speedup 1.0000x reference)
//
#include <hip/hip_runtime.h>

#define T_STEPS 12
#define NN 100000
#define EE 3200000
#define HD 64
#define OD 32

typedef __attribute__((ext_vector_type(8))) short short8;
typedef __attribute__((ext_vector_type(4))) float f32x4;

__device__ __forceinline__ unsigned short f2b(float x) {
  union { float f; unsigned int u; } v; v.f = x;
  unsigned int r = v.u + 0x7FFFu + ((v.u >> 16) & 1u);
  return (unsigned short)(r >> 16);
}

__device__ __forceinline__ float sigm(float x) {
  x = fminf(fmaxf(x, -30.f), 30.f);
  return 1.0f / (1.0f + __expf(-x));
}
__device__ __forceinline__ float tanh_f(float x) {
  x = fminf(fmaxf(x, -15.f), 15.f);
  float e = __expf(2.0f * x);
  return (e - 1.0f) / (e + 1.0f);
}

// ---------------- CSR build ----------------
__global__ __launch_bounds__(256) void k_count(const int* __restrict__ dst,
                                               int* __restrict__ deg, int E) {
  int e = blockIdx.x * 256 + threadIdx.x;
  if (e < E) atomicAdd(&deg[dst[e]], 1);
}

__global__ __launch_bounds__(1024) void k_scan(const int* __restrict__ deg,
                                               int* __restrict__ row_ptr,
                                               int* __restrict__ cursor,
                                               float* __restrict__ deg_inv, int n) {
  __shared__ int buf[1024];
  int tid = threadIdx.x;
  int carry = 0;
  for (int base = 0; base < n; base += 4096) {
    int idx0 = base + tid * 4;
    int v0 = 0, v1 = 0, v2 = 0, v3 = 0;
    if (idx0 + 0 < n) v0 = deg[idx0 + 0];
    if (idx0 + 1 < n) v1 = deg[idx0 + 1];
    if (idx0 + 2 < n) v2 = deg[idx0 + 2];
    if (idx0 + 3 < n) v3 = deg[idx0 + 3];
    int s = v0 + v1 + v2 + v3;
    buf[tid] = s;
    __syncthreads();
    for (int off = 1; off < 1024; off <<= 1) {
      int t = (tid >= off) ? buf[tid - off] : 0;
      __syncthreads();
      buf[tid] += t;
      __syncthreads();
    }
    int excl = buf[tid] - s + carry;
    int total = buf[1023];
    __syncthreads();
    int run = excl;
    int vv[4] = {v0, v1, v2, v3};
#pragma unroll
    for (int j = 0; j < 4; ++j) {
      int i = idx0 + j;
      if (i < n) {
        row_ptr[i] = run;
        cursor[i] = run;
        deg_inv[i] = vv[j] ? (1.0f / (float)vv[j]) : 0.0f;
        run += vv[j];
      }
    }
    carry += total;
  }
  if (tid == 0) row_ptr[n] = carry;
}

__global__ __launch_bounds__(256) void k_scatter(const int* __restrict__ src,
                                                 const int* __restrict__ dst,
                                                 int* __restrict__ cursor,
                                                 int* __restrict__ csr, int E) {
  int e = blockIdx.x * 256 + threadIdx.x;
  if (e < E) {
    int p = atomicAdd(&cursor[dst[e]], 1);
    csr[p] = src[e];
  }
}

// ---------------- weight prep: fragment-ordered bf16 B ----------------
// Bprep[l][kb(8)][fi(16)][lane(64)][j(8)]  = B[fc][c],
//   fc = kb*32 + (lane>>4)*8 + j   (concat-K: [inp|xagg|h|hagg])
//   c  = fi*16 + (lane&15)         (col: g*64 + k)
__global__ __launch_bounds__(256) void k_prep(const float* __restrict__ Wxs,
                                              const float* __restrict__ Wxn,
                                              const float* __restrict__ Whs,
                                              const float* __restrict__ Whn,
                                              unsigned short* __restrict__ bprep) {
  int idx = blockIdx.x * 256 + threadIdx.x;  // 0..131071
  int l = idx >> 16;
  int kb = (idx >> 13) & 7;
  int fi = (idx >> 9) & 15;
  int ln = (idx >> 3) & 63;
  int j = idx & 7;
  int fc = kb * 32 + ((ln >> 4) << 3) + j;
  int c = fi * 16 + (ln & 15);
  int t = fc >> 6, f = fc & 63, g = c >> 6, kk = c & 63;
  const float* tabs[4] = {Wxs, Wxn, Whs, Whn};
  float v = tabs[t][((size_t)(l * 4 + g) * 64 + f) * 64 + kk];
  bprep[idx] = f2b(v);
}

// ---------------- dual mean aggregation ----------------
__global__ __launch_bounds__(256) void k_agg_dual(const float* __restrict__ fA,
                                                  const float* __restrict__ fB,
                                                  const int* __restrict__ row_ptr,
                                                  const int* __restrict__ csr,
                                                  const float* __restrict__ deg_inv,
                                                  float* __restrict__ outA,
                                                  float* __restrict__ outB, int n_nodes) {
  int node = (int)((blockIdx.x * blockDim.x + threadIdx.x) >> 6);
  if (node >= n_nodes) return;
  int lane = threadIdx.x & 63;
  int g = lane >> 4, m = lane & 15;
  int start = row_ptr[node], end = row_ptr[node + 1];
  float ax = 0, ay = 0, az = 0, aw = 0;
  float bx = 0, by = 0, bz = 0, bw = 0;
  for (int e0 = start; e0 < end; e0 += 4) {
    int e = e0 + g;
    if (e < end) {
      int s = csr[e];
      const float4 va = *reinterpret_cast<const float4*>(fA + (size_t)s * HD + m * 4);
      const float4 vb = *reinterpret_cast<const float4*>(fB + (size_t)s * HD + m * 4);
      ax += va.x; ay += va.y; az += va.z; aw += va.w;
      bx += vb.x; by += vb.y; bz += vb.z; bw += vb.w;
    }
  }
#pragma unroll
  for (int off = 16; off < 64; off <<= 1) {
    ax += __shfl_xor(ax, off); ay += __shfl_xor(ay, off);
    az += __shfl_xor(az, off); aw += __shfl_xor(aw, off);
    bx += __shfl_xor(bx, off); by += __shfl_xor(by, off);
    bz += __shfl_xor(bz, off); bw += __shfl_xor(bw, off);
  }
  if (g == 0) {
    float sc = deg_inv[node];
    float4 oa = make_float4(ax * sc, ay * sc, az * sc, aw * sc);
    float4 ob = make_float4(bx * sc, by * sc, bz * sc, bw * sc);
    *reinterpret_cast<float4*>(outA + (size_t)node * HD + m * 4) = oa;
    *reinterpret_cast<float4*>(outB + (size_t)node * HD + m * 4) = ob;
  }
}

// ---------------- fused gate GEMM + LSTM pointwise ----------------
// tile: 64 nodes x 256 cols (4 gates x 64), K=256 concat. 4 waves; wave w
// owns nodes [nb+16w, nb+16w+16). A staged in LDS in fragment order.
__global__ __launch_bounds__(256) void k_gates(const float* __restrict__ inp,
                                               const float* __restrict__ xagg,
                                               const float* __restrict__ hagg,
                                               float* __restrict__ hst,
                                               float* __restrict__ cst,
                                               const unsigned short* __restrict__ bprep,
                                               const float* __restrict__ wc,
                                               const float* __restrict__ bias,
                                               int n_nodes) {
  __shared__ unsigned short Asm[64 * 256];  // 32 KB frag-order [kb][w][lane][j]
  __shared__ unsigned short Bsm[32 * 256];  // 16 KB one K-chunk [fi][lane][j]
  const int tid = threadIdx.x;
  const int lane = tid & 63;
  const int w = tid >> 6;
  const int nb = blockIdx.x * 64;

  const float* tabs[4] = {inp, xagg, hst, hagg};
#pragma unroll
  for (int tb = 0; tb < 4; ++tb) {
    const float* sp = tabs[tb];
#pragma unroll
    for (int r = 0; r < 4; ++r) {
      int flat = r * 256 + tid;  // float4 slot: node = flat>>4, fq = flat&15
      int nl = flat >> 4;
      int fq = flat & 15;
      int gn = nb + nl;
      float4 v = make_float4(0.f, 0.f, 0.f, 0.f);
      if (gn < n_nodes) v = *reinterpret_cast<const float4*>(sp + (size_t)gn * HD + fq * 4);
      int fc0 = tb * 64 + fq * 4;
      int kb = fc0 >> 5;
      int kg = (fc0 >> 3) & 3;
      int j0 = fc0 & 7;  // 0 or 4
      int dl = kg * 16 + (nl & 15);
      int wd = nl >> 4;
      ushort4 b4;
      b4.x = f2b(v.x); b4.y = f2b(v.y); b4.z = f2b(v.z); b4.w = f2b(v.w);
      *reinterpret_cast<ushort4*>(&Asm[(((kb * 4 + wd) * 64 + dl) << 3) + j0]) = b4;
    }
  }

  f32x4 acc[16];
  f32x4 z4 = {0.f, 0.f, 0.f, 0.f};
#pragma unroll
  for (int i = 0; i < 16; ++i) acc[i] = z4;

  for (int kb = 0; kb < 8; ++kb) {
    __syncthreads();
#pragma unroll
    for (int r = 0; r < 4; ++r) {
      int off = (r * 256 + tid) << 3;  // ushort index, 16B per thread
      *reinterpret_cast<uint4*>(&Bsm[off]) =
          *reinterpret_cast<const uint4*>(&bprep[(kb << 13) + off]);
    }
    __syncthreads();
    short8 af = *reinterpret_cast<const short8*>(&Asm[((kb * 4 + w) * 64 + lane) << 3]);
#pragma unroll
    for (int fi = 0; fi < 16; ++fi) {
      short8 bf = *reinterpret_cast<const short8*>(&Bsm[(fi * 64 + lane) << 3]);
      acc[fi] = __builtin_amdgcn_mfma_f32_16x16x32_bf16(af, bf, acc[fi], 0, 0, 0);
    }
  }

  // epilogue: lane holds (n = nb + 16w + (lane>>4)*4 + r, k = kf*16 + (lane&15))
  const int cl = lane & 15;
  const int rowg = lane >> 4;
#pragma unroll
  for (int kf = 0; kf < 4; ++kf) {
    int k = kf * 16 + cl;
    float wci = wc[k], wcf = wc[64 + k], wco = wc[128 + k];
    float bi = bias[k], bff = bias[64 + k], bc = bias[128 + k], bo = bias[192 + k];
#pragma unroll
    for (int r = 0; r < 4; ++r) {
      int n = nb + w * 16 + rowg * 4 + r;
      if (n < n_nodes) {
        size_t off = (size_t)n * HD + k;
        float c_old = cst[off];
        float pi = acc[0 + kf][r];
        float pf = acc[4 + kf][r];
        float pc = acc[8 + kf][r];
        float po = acc[12 + kf][r];
        float ig = sigm(pi + wci * c_old + bi);
        float fg = sigm(pf + wcf * c_old + bff);
        float ct = tanh_f(pc + bc);
        float nc = fg * c_old + ig * ct;
        float og = sigm(po + wco * nc + bo);
        float nh = og * tanh_f(nc);
        cst[off] = nc;
        hst[off] = nh;
      }
    }
  }
}

// ---------------- output projection ----------------
__global__ __launch_bounds__(256) void k_outproj(const float* __restrict__ h1,
                                                 const float* __restrict__ Wout,
                                                 const float* __restrict__ bout,
                                                 float* __restrict__ out, int n_nodes) {
  __shared__ float Wl[64 * 32];
  __shared__ float hs[8 * 64];
  int tid = threadIdx.x;
#pragma unroll
  for (int r = 0; r < 8; ++r) Wl[r * 256 + tid] = Wout[r * 256 + tid];
  int nb = blockIdx.x * 8;
#pragma unroll
  for (int r = 0; r < 2; ++r) {
    int i = r * 256 + tid;
    int n = nb + (i >> 6);
    hs[i] = (n < n_nodes) ? h1[(size_t)n * HD + (i & 63)] : 0.f;
  }
  __syncthreads();
  int nl = tid >> 5, o = tid & 31;
  int n = nb + nl;
  float acc = bout[o];
#pragma unroll
  for (int k = 0; k < 64; ++k) acc += hs[nl * 64 + k] * Wl[k * 32 + o];
  if (n < n_nodes) out[(size_t)n * OD + o] = acc;
}

extern "C" void kernel_launch(void* const* d_in, const int* in_sizes, int n_in,
                              void* d_out, int out_size, void* d_ws, size_t ws_size,
                              hipStream_t stream) {
  const float* x = (const float*)d_in[0];
  const float* h0 = (const float*)d_in[1];
  const float* c0 = (const float*)d_in[2];
  const float* Wxs = (const float*)d_in[3];
  const float* Wxn = (const float*)d_in[4];
  const float* Whs = (const float*)d_in[5];
  const float* Whn = (const float*)d_in[6];
  const float* wc = (const float*)d_in[7];
  const float* bias = (const float*)d_in[8];
  const float* Wout = (const float*)d_in[9];
  const float* bout = (const float*)d_in[10];
  const int* src = (const int*)d_in[11];
  const int* dst = (const int*)d_in[12];

  float* out = (float*)d_out;
  float* outs = out;                                   // [T][N][O]
  float* hstate = out + (size_t)T_STEPS * NN * OD;     // [2][N][64]
  float* cstate = hstate + (size_t)2 * NN * HD;        // [2][N][64]

  char* p = (char*)d_ws;
  auto alloc = [&](size_t bytes) {
    char* r = p;
    p += (bytes + 255) & ~(size_t)255;
    return r;
  };
  int* csr = (int*)alloc((size_t)EE * 4);
  int* row_ptr = (int*)alloc((size_t)(NN + 1) * 4);
  int* cursor = (int*)alloc((size_t)NN * 4);
  int* deg = (int*)alloc((size_t)NN * 4);
  float* deg_inv = (float*)alloc((size_t)NN * 4);
  float* xagg = (float*)alloc((size_t)NN * HD * 4);
  float* hagg = (float*)alloc((size_t)NN * HD * 4);
  unsigned short* bprep = (unsigned short*)alloc((size_t)2 * 256 * 256 * 2);

  // CSR build + weight prep + state init
  hipMemsetAsync(deg, 0, (size_t)NN * 4, stream);
  k_count<<<EE / 256, 256, 0, stream>>>(dst, deg, EE);
  k_scan<<<1, 1024, 0, stream>>>(deg, row_ptr, cursor, deg_inv, NN);
  k_scatter<<<EE / 256, 256, 0, stream>>>(src, dst, cursor, csr, EE);
  k_prep<<<512, 256, 0, stream>>>(Wxs, Wxn, Whs, Whn, bprep);
  hipMemcpyAsync(hstate, h0, (size_t)2 * NN * HD * 4, hipMemcpyDeviceToDevice, stream);
  hipMemcpyAsync(cstate, c0, (size_t)2 * NN * HD * 4, hipMemcpyDeviceToDevice, stream);

  const int agg_grid = (NN + 3) / 4;       // 4 nodes (waves) per block
  const int gate_grid = (NN + 63) / 64;    // 64 nodes per block
  const int proj_grid = (NN + 7) / 8;      // 8 nodes per block

  for (int t = 0; t < T_STEPS; ++t) {
    const float* inp0 = x + (size_t)t * NN * HD;
    // layer 0
    k_agg_dual<<<agg_grid, 256, 0, stream>>>(inp0, hstate, row_ptr, csr, deg_inv,
                                             xagg, hagg, NN);
    k_gates<<<gate_grid, 256, 0, stream>>>(inp0, xagg, hagg, hstate, cstate,
                                           bprep, wc, bias, NN);
    // layer 1 (inp = new h of layer 0, in-place at hstate[0])
    k_agg_dual<<<agg_grid, 256, 0, stream>>>(hstate, hstate + (size_t)NN * HD,
                                             row_ptr, csr, deg_inv, xagg, hagg, NN);
    k_gates<<<gate_grid, 256, 0, stream>>>(hstate, xagg, hagg,
                                           hstate + (size_t)NN * HD,
                                           cstate + (size_t)NN * HD,
                                           bprep + 65536, wc + 192, bias + 256, NN);
    k_outproj<<<proj_grid, 256, 0, stream>>>(hstate + (size_t)NN * HD, Wout, bout,
                                             outs + (size_t)t * NN * OD, NN);
  }
}

// Round 2
// 4244.667 us; speedup vs baseline: 1.7606x; 1.7606x over previous
//
#include <hip/hip_runtime.h>

#define T_STEPS 12
#define NN 100000
#define EE 3200000
#define HD 64
#define OD 32

typedef __attribute__((ext_vector_type(8))) short short8;
typedef __attribute__((ext_vector_type(4))) float f32x4;
typedef unsigned short u16;

__device__ __forceinline__ u16 f2b(float x) {
  union { float f; unsigned u; } v; v.f = x;
  unsigned r = v.u + 0x7FFFu + ((v.u >> 16) & 1u);
  return (u16)(r >> 16);
}
__device__ __forceinline__ float b2f(u16 u) {
  union { unsigned u; float f; } v; v.u = ((unsigned)u) << 16;
  return v.f;
}
__device__ __forceinline__ float sigm(float x) {
  x = fminf(fmaxf(x, -30.f), 30.f);
  return 1.0f / (1.0f + __expf(-x));
}
__device__ __forceinline__ float tanh_f(float x) {
  x = fminf(fmaxf(x, -15.f), 15.f);
  float e = __expf(2.0f * x);
  return (e - 1.0f) / (e + 1.0f);
}

// ---------------- CSR build ----------------
__global__ __launch_bounds__(256) void k_count(const int* __restrict__ dst,
                                               int* __restrict__ deg, int E) {
  int e = blockIdx.x * 256 + threadIdx.x;
  if (e < E) atomicAdd(&deg[dst[e]], 1);
}

__global__ __launch_bounds__(1024) void k_scan(const int* __restrict__ deg,
                                               int* __restrict__ row_ptr,
                                               int* __restrict__ cursor,
                                               float* __restrict__ deg_inv, int n) {
  __shared__ int buf[1024];
  int tid = threadIdx.x;
  int carry = 0;
  for (int base = 0; base < n; base += 4096) {
    int idx0 = base + tid * 4;
    int v0 = 0, v1 = 0, v2 = 0, v3 = 0;
    if (idx0 + 0 < n) v0 = deg[idx0 + 0];
    if (idx0 + 1 < n) v1 = deg[idx0 + 1];
    if (idx0 + 2 < n) v2 = deg[idx0 + 2];
    if (idx0 + 3 < n) v3 = deg[idx0 + 3];
    int s = v0 + v1 + v2 + v3;
    buf[tid] = s;
    __syncthreads();
    for (int off = 1; off < 1024; off <<= 1) {
      int t = (tid >= off) ? buf[tid - off] : 0;
      __syncthreads();
      buf[tid] += t;
      __syncthreads();
    }
    int excl = buf[tid] - s + carry;
    int total = buf[1023];
    __syncthreads();
    int run = excl;
    int vv[4] = {v0, v1, v2, v3};
#pragma unroll
    for (int j = 0; j < 4; ++j) {
      int i = idx0 + j;
      if (i < n) {
        row_ptr[i] = run;
        cursor[i] = run;
        deg_inv[i] = vv[j] ? (1.0f / (float)vv[j]) : 0.0f;
        run += vv[j];
      }
    }
    carry += total;
  }
  if (tid == 0) row_ptr[n] = carry;
}

__global__ __launch_bounds__(256) void k_scatter(const int* __restrict__ src,
                                                 const int* __restrict__ dst,
                                                 int* __restrict__ cursor,
                                                 int* __restrict__ csr, int E) {
  int e = blockIdx.x * 256 + threadIdx.x;
  if (e < E) {
    int p = atomicAdd(&cursor[dst[e]], 1);
    csr[p] = src[e];
  }
}

// ---------------- weight prep: fragment-ordered bf16 B ----------------
// bprep[l][kb(8)][fi(16)][lane(64)][j(8)] = B[fc][col(fi,lane)]
//   fc  = kb*32 + (lane>>4)*8 + j           (concat-K: [inp|xagg|h|hagg])
//   col: gate g = fi&3, k = (fi>>2)*16 + (lane&15)
//   (so wave w = fi>>2 owns k-slice [16w,16w+16) holding ALL 4 gates)
__global__ __launch_bounds__(256) void k_prep(const float* __restrict__ Wxs,
                                              const float* __restrict__ Wxn,
                                              const float* __restrict__ Whs,
                                              const float* __restrict__ Whn,
                                              u16* __restrict__ bprep) {
  int idx = blockIdx.x * 256 + threadIdx.x;  // 0..131071
  int l = idx >> 16;
  int kb = (idx >> 13) & 7;
  int fi = (idx >> 9) & 15;
  int ln = (idx >> 3) & 63;
  int j = idx & 7;
  int fc = kb * 32 + ((ln >> 4) << 3) + j;
  int g = fi & 3;
  int kk = ((fi >> 2) << 4) + (ln & 15);
  int t = fc >> 6, f = fc & 63;
  const float* tabs[4] = {Wxs, Wxn, Whs, Whn};
  bprep[idx] = f2b(tabs[t][((size_t)(l * 4 + g) * 64 + f) * 64 + kk]);
}

// ---------------- per-step x -> bf16 into pair buffer ----------------
__global__ __launch_bounds__(256) void k_convx(const float* __restrict__ x,
                                               u16* __restrict__ pa) {
  int idx = blockIdx.x * 256 + threadIdx.x;  // N*8
  int n = idx >> 3, j = idx & 7;
  float4 v0 = *reinterpret_cast<const float4*>(x + (size_t)n * 64 + j * 8);
  float4 v1 = *reinterpret_cast<const float4*>(x + (size_t)n * 64 + j * 8 + 4);
  short8 o;
  o[0] = (short)f2b(v0.x); o[1] = (short)f2b(v0.y);
  o[2] = (short)f2b(v0.z); o[3] = (short)f2b(v0.w);
  o[4] = (short)f2b(v1.x); o[5] = (short)f2b(v1.y);
  o[6] = (short)f2b(v1.z); o[7] = (short)f2b(v1.w);
  *reinterpret_cast<short8*>(pa + (size_t)n * 128 + j * 8) = o;
}

// ---------------- init h (both layers) -> bf16 buffers ----------------
__global__ __launch_bounds__(256) void k_inith(const float* __restrict__ h0,
                                               u16* __restrict__ H0,
                                               u16* __restrict__ PA) {
  int idx = blockIdx.x * 256 + threadIdx.x;  // N*8
  int n = idx >> 3, j = idx & 7;
#pragma unroll
  for (int L = 0; L < 2; ++L) {
    float4 v0 = *reinterpret_cast<const float4*>(h0 + (size_t)L * NN * 64 + (size_t)n * 64 + j * 8);
    float4 v1 = *reinterpret_cast<const float4*>(h0 + (size_t)L * NN * 64 + (size_t)n * 64 + j * 8 + 4);
    short8 o;
    o[0] = (short)f2b(v0.x); o[1] = (short)f2b(v0.y);
    o[2] = (short)f2b(v0.z); o[3] = (short)f2b(v0.w);
    o[4] = (short)f2b(v1.x); o[5] = (short)f2b(v1.y);
    o[6] = (short)f2b(v1.z); o[7] = (short)f2b(v1.w);
    if (L == 0)
      *reinterpret_cast<short8*>(H0 + (size_t)n * 64 + j * 8) = o;
    else
      *reinterpret_cast<short8*>(PA + (size_t)n * 128 + 64 + j * 8) = o;
  }
}

// ---------------- dual mean aggregation over [N][128] bf16 pair ----------------
__global__ __launch_bounds__(256) void k_agg_pair(const u16* __restrict__ P,
                                                  const int* __restrict__ row_ptr,
                                                  const int* __restrict__ csr,
                                                  const float* __restrict__ deg_inv,
                                                  u16* __restrict__ outp) {
  int node = blockIdx.x * 4 + (threadIdx.x >> 6);
  int lane = threadIdx.x & 63;
  int g = lane >> 4, m = lane & 15;  // 4 edge slots x 16B lanes
  int start = row_ptr[node], end = row_ptr[node + 1];
  float a0 = 0, a1 = 0, a2 = 0, a3 = 0, a4 = 0, a5 = 0, a6 = 0, a7 = 0;
  int e = start + g;
  for (; e + 4 < end; e += 8) {
    int s0 = csr[e], s1 = csr[e + 4];
    short8 v0 = *reinterpret_cast<const short8*>(P + (size_t)s0 * 128 + m * 8);
    short8 v1 = *reinterpret_cast<const short8*>(P + (size_t)s1 * 128 + m * 8);
    a0 += b2f((u16)v0[0]) + b2f((u16)v1[0]);
    a1 += b2f((u16)v0[1]) + b2f((u16)v1[1]);
    a2 += b2f((u16)v0[2]) + b2f((u16)v1[2]);
    a3 += b2f((u16)v0[3]) + b2f((u16)v1[3]);
    a4 += b2f((u16)v0[4]) + b2f((u16)v1[4]);
    a5 += b2f((u16)v0[5]) + b2f((u16)v1[5]);
    a6 += b2f((u16)v0[6]) + b2f((u16)v1[6]);
    a7 += b2f((u16)v0[7]) + b2f((u16)v1[7]);
  }
  if (e < end) {
    int s0 = csr[e];
    short8 v0 = *reinterpret_cast<const short8*>(P + (size_t)s0 * 128 + m * 8);
    a0 += b2f((u16)v0[0]); a1 += b2f((u16)v0[1]);
    a2 += b2f((u16)v0[2]); a3 += b2f((u16)v0[3]);
    a4 += b2f((u16)v0[4]); a5 += b2f((u16)v0[5]);
    a6 += b2f((u16)v0[6]); a7 += b2f((u16)v0[7]);
  }
#pragma unroll
  for (int off = 16; off < 64; off <<= 1) {
    a0 += __shfl_xor(a0, off); a1 += __shfl_xor(a1, off);
    a2 += __shfl_xor(a2, off); a3 += __shfl_xor(a3, off);
    a4 += __shfl_xor(a4, off); a5 += __shfl_xor(a5, off);
    a6 += __shfl_xor(a6, off); a7 += __shfl_xor(a7, off);
  }
  if (g == 0) {
    float sc = deg_inv[node];
    short8 o;
    o[0] = (short)f2b(a0 * sc); o[1] = (short)f2b(a1 * sc);
    o[2] = (short)f2b(a2 * sc); o[3] = (short)f2b(a3 * sc);
    o[4] = (short)f2b(a4 * sc); o[5] = (short)f2b(a5 * sc);
    o[6] = (short)f2b(a6 * sc); o[7] = (short)f2b(a7 * sc);
    *reinterpret_cast<short8*>(outp + (size_t)node * 128 + m * 8) = o;
  }
}

// ---------------- single mean aggregation over [N][64] bf16 ----------------
__global__ __launch_bounds__(256) void k_agg_single(const u16* __restrict__ P,
                                                    const int* __restrict__ row_ptr,
                                                    const int* __restrict__ csr,
                                                    const float* __restrict__ deg_inv,
                                                    u16* __restrict__ outp) {
  int node = blockIdx.x * 4 + (threadIdx.x >> 6);
  int lane = threadIdx.x & 63;
  int g = lane >> 3, m = lane & 7;  // 8 edge slots x 8 lanes (16B each)
  int start = row_ptr[node], end = row_ptr[node + 1];
  float a0 = 0, a1 = 0, a2 = 0, a3 = 0, a4 = 0, a5 = 0, a6 = 0, a7 = 0;
  int e = start + g;
  for (; e + 8 < end; e += 16) {
    int s0 = csr[e], s1 = csr[e + 8];
    short8 v0 = *reinterpret_cast<const short8*>(P + (size_t)s0 * 64 + m * 8);
    short8 v1 = *reinterpret_cast<const short8*>(P + (size_t)s1 * 64 + m * 8);
    a0 += b2f((u16)v0[0]) + b2f((u16)v1[0]);
    a1 += b2f((u16)v0[1]) + b2f((u16)v1[1]);
    a2 += b2f((u16)v0[2]) + b2f((u16)v1[2]);
    a3 += b2f((u16)v0[3]) + b2f((u16)v1[3]);
    a4 += b2f((u16)v0[4]) + b2f((u16)v1[4]);
    a5 += b2f((u16)v0[5]) + b2f((u16)v1[5]);
    a6 += b2f((u16)v0[6]) + b2f((u16)v1[6]);
    a7 += b2f((u16)v0[7]) + b2f((u16)v1[7]);
  }
  if (e < end) {
    int s0 = csr[e];
    short8 v0 = *reinterpret_cast<const short8*>(P + (size_t)s0 * 64 + m * 8);
    a0 += b2f((u16)v0[0]); a1 += b2f((u16)v0[1]);
    a2 += b2f((u16)v0[2]); a3 += b2f((u16)v0[3]);
    a4 += b2f((u16)v0[4]); a5 += b2f((u16)v0[5]);
    a6 += b2f((u16)v0[6]); a7 += b2f((u16)v0[7]);
  }
#pragma unroll
  for (int off = 8; off < 64; off <<= 1) {
    a0 += __shfl_xor(a0, off); a1 += __shfl_xor(a1, off);
    a2 += __shfl_xor(a2, off); a3 += __shfl_xor(a3, off);
    a4 += __shfl_xor(a4, off); a5 += __shfl_xor(a5, off);
    a6 += __shfl_xor(a6, off); a7 += __shfl_xor(a7, off);
  }
  if (g == 0) {
    float sc = deg_inv[node];
    short8 o;
    o[0] = (short)f2b(a0 * sc); o[1] = (short)f2b(a1 * sc);
    o[2] = (short)f2b(a2 * sc); o[3] = (short)f2b(a3 * sc);
    o[4] = (short)f2b(a4 * sc); o[5] = (short)f2b(a5 * sc);
    o[6] = (short)f2b(a6 * sc); o[7] = (short)f2b(a7 * sc);
    *reinterpret_cast<short8*>(outp + (size_t)node * 64 + m * 8) = o;
  }
}

// ---------------- fused gate GEMM + LSTM pointwise (zero LDS / barriers) ----
// Block = 64 nodes. Wave w owns k-slice [16w,16w+16) of ALL 4 gates:
// B (its column quarter, all K) lives in 128 persistent VGPRs; A fragments
// are register-direct 16B global loads from the 4 bf16 source tables.
__global__ __launch_bounds__(256, 2) void k_gates(
    const u16* __restrict__ tab0, const u16* __restrict__ tab1,
    u16* __restrict__ tab2, const u16* __restrict__ tab3,
    int ld0, int ld1, int ld2, int ld3,
    float* __restrict__ cst, float* __restrict__ hf32,
    const u16* __restrict__ bprepl,
    const float* __restrict__ wcl, const float* __restrict__ biasl,
    int n_nodes, int writef32) {
  const int tid = threadIdx.x;
  const int lane = tid & 63;
  const int w = tid >> 6;
  const int nb = blockIdx.x * 64;
  const int cl = lane & 15;
  const int kg = lane >> 4;

  short8 breg[8][4];
#pragma unroll
  for (int kb = 0; kb < 8; ++kb)
#pragma unroll
    for (int fl = 0; fl < 4; ++fl)
      breg[kb][fl] = *reinterpret_cast<const short8*>(
          bprepl + (kb << 13) + (((w << 2) + fl) << 9) + (lane << 3));

  const u16* tabs[4] = {tab0, tab1, tab2, tab3};
  const int lds[4] = {ld0, ld1, ld2, ld3};
  int gnc[4];
#pragma unroll
  for (int rg = 0; rg < 4; ++rg) {
    int g = nb + rg * 16 + cl;
    gnc[rg] = (g < n_nodes) ? g : (n_nodes - 1);
  }

  f32x4 acc[4][4];
  f32x4 z4 = {0.f, 0.f, 0.f, 0.f};
#pragma unroll
  for (int a = 0; a < 4; ++a)
#pragma unroll
    for (int b = 0; b < 4; ++b) acc[a][b] = z4;

  const int koff = kg << 3;
#pragma unroll
  for (int kb = 0; kb < 8; ++kb) {
    const u16* tp = tabs[kb >> 1];
    const int ld = lds[kb >> 1];
    const int idx = ((kb & 1) << 5) + koff;
#pragma unroll
    for (int rg = 0; rg < 4; ++rg) {
      short8 a = *reinterpret_cast<const short8*>(tp + (size_t)gnc[rg] * ld + idx);
      acc[rg][0] = __builtin_amdgcn_mfma_f32_16x16x32_bf16(a, breg[kb][0], acc[rg][0], 0, 0, 0);
      acc[rg][1] = __builtin_amdgcn_mfma_f32_16x16x32_bf16(a, breg[kb][1], acc[rg][1], 0, 0, 0);
      acc[rg][2] = __builtin_amdgcn_mfma_f32_16x16x32_bf16(a, breg[kb][2], acc[rg][2], 0, 0, 0);
      acc[rg][3] = __builtin_amdgcn_mfma_f32_16x16x32_bf16(a, breg[kb][3], acc[rg][3], 0, 0, 0);
    }
  }

  const int k = (w << 4) + cl;
  const float wci = wcl[k], wcf = wcl[64 + k], wco = wcl[128 + k];
  const float bi = biasl[k], bfg = biasl[64 + k], bc = biasl[128 + k], bo = biasl[192 + k];
#pragma unroll
  for (int rg = 0; rg < 4; ++rg) {
#pragma unroll
    for (int r = 0; r < 4; ++r) {
      int n = nb + rg * 16 + kg * 4 + r;
      if (n < n_nodes) {
        size_t off = (size_t)n * 64 + k;
        float c_old = cst[off];
        float ig = sigm(acc[rg][0][r] + wci * c_old + bi);
        float fg = sigm(acc[rg][1][r] + wcf * c_old + bfg);
        float ct = tanh_f(acc[rg][2][r] + bc);
        float nc = fg * c_old + ig * ct;
        float og = sigm(acc[rg][3][r] + wco * nc + bo);
        float nh = og * tanh_f(nc);
        cst[off] = nc;
        tab2[(size_t)n * ld2 + k] = (u16)f2b(nh);
        if (writef32) hf32[off] = nh;
      }
    }
  }
}

// ---------------- output projection (reads bf16 h1, stride 128) ----------------
__global__ __launch_bounds__(256) void k_outproj(const u16* __restrict__ h1,
                                                 const float* __restrict__ Wout,
                                                 const float* __restrict__ bout,
                                                 float* __restrict__ out, int n_nodes) {
  __shared__ float Wl[64 * 32];
  __shared__ float hs[8 * 64];
  int tid = threadIdx.x;
#pragma unroll
  for (int r = 0; r < 8; ++r) Wl[r * 256 + tid] = Wout[r * 256 + tid];
  int nb = blockIdx.x * 8;
#pragma unroll
  for (int r = 0; r < 2; ++r) {
    int i = r * 256 + tid;
    int n = nb + (i >> 6);
    hs[i] = (n < n_nodes) ? b2f(h1[(size_t)n * 128 + (i & 63)]) : 0.f;
  }
  __syncthreads();
  int nl = tid >> 5, o = tid & 31;
  int n = nb + nl;
  float acc = bout[o];
#pragma unroll
  for (int kk = 0; kk < 64; ++kk) acc += hs[nl * 64 + kk] * Wl[kk * 32 + o];
  if (n < n_nodes) out[(size_t)n * OD + o] = acc;
}

extern "C" void kernel_launch(void* const* d_in, const int* in_sizes, int n_in,
                              void* d_out, int out_size, void* d_ws, size_t ws_size,
                              hipStream_t stream) {
  const float* x = (const float*)d_in[0];
  const float* h0 = (const float*)d_in[1];
  const float* c0 = (const float*)d_in[2];
  const float* Wxs = (const float*)d_in[3];
  const float* Wxn = (const float*)d_in[4];
  const float* Whs = (const float*)d_in[5];
  const float* Whn = (const float*)d_in[6];
  const float* wc = (const float*)d_in[7];
  const float* bias = (const float*)d_in[8];
  const float* Wout = (const float*)d_in[9];
  const float* bout = (const float*)d_in[10];
  const int* src = (const int*)d_in[11];
  const int* dst = (const int*)d_in[12];

  float* out = (float*)d_out;
  float* outs = out;                                   // [T][N][O]
  float* hstate = out + (size_t)T_STEPS * NN * OD;     // [2][N][64] fp32 (final)
  float* cstate = hstate + (size_t)2 * NN * HD;        // [2][N][64] fp32 (live)

  char* p = (char*)d_ws;
  auto alloc = [&](size_t bytes) {
    char* r = p;
    p += (bytes + 255) & ~(size_t)255;
    return r;
  };
  int* csr = (int*)alloc((size_t)EE * 4);
  int* row_ptr = (int*)alloc((size_t)(NN + 1) * 4);
  int* cursor = (int*)alloc((size_t)NN * 4);
  int* deg = (int*)alloc((size_t)NN * 4);
  float* deg_inv = (float*)alloc((size_t)NN * 4);
  u16* PA = (u16*)alloc((size_t)NN * 128 * 2);    // [x_t | h_l1] bf16
  u16* H0 = (u16*)alloc((size_t)NN * 64 * 2);     // h_l0 bf16
  u16* AGGP = (u16*)alloc((size_t)NN * 128 * 2);  // [agg(x) | agg(h_l1)]
  u16* AGGH = (u16*)alloc((size_t)NN * 64 * 2);   // agg(h_l0) (cached across steps)
  u16* bprep = (u16*)alloc((size_t)2 * 65536 * 2);

  // prologue: CSR build + weight prep + state init
  hipMemsetAsync(deg, 0, (size_t)NN * 4, stream);
  k_count<<<EE / 256, 256, 0, stream>>>(dst, deg, EE);
  k_scan<<<1, 1024, 0, stream>>>(deg, row_ptr, cursor, deg_inv, NN);
  k_scatter<<<EE / 256, 256, 0, stream>>>(src, dst, cursor, csr, EE);
  k_prep<<<512, 256, 0, stream>>>(Wxs, Wxn, Whs, Whn, bprep);
  k_inith<<<NN * 8 / 256, 256, 0, stream>>>(h0, H0, PA);
  hipMemcpyAsync(cstate, c0, (size_t)2 * NN * HD * 4, hipMemcpyDeviceToDevice, stream);
  // initial agg(h_l0) for step 0's layer-0 h_agg
  k_agg_single<<<NN / 4, 256, 0, stream>>>(H0, row_ptr, csr, deg_inv, AGGH);

  for (int t = 0; t < T_STEPS; ++t) {
    int wf = (t == T_STEPS - 1) ? 1 : 0;
    k_convx<<<NN * 8 / 256, 256, 0, stream>>>(x + (size_t)t * NN * HD, PA);
    // dual agg: mean(x_t) and mean(h_l1_old)
    k_agg_pair<<<NN / 4, 256, 0, stream>>>(PA, row_ptr, csr, deg_inv, AGGP);
    // layer 0: inp=x_t(PA,0), xagg=AGGP(0), h=H0 (in-place), hagg=AGGH (cached)
    k_gates<<<(NN + 63) / 64, 256, 0, stream>>>(
        PA, AGGP, H0, AGGH, 128, 128, 64, 64,
        cstate, hstate, bprep, wc, bias, NN, wf);
    // agg of new h_l0: serves layer-1 x-side now AND layer-0 h-side next step
    k_agg_single<<<NN / 4, 256, 0, stream>>>(H0, row_ptr, csr, deg_inv, AGGH);
    // layer 1: inp=H0, xagg=AGGH, h=PA+64 (in-place), hagg=AGGP+64
    k_gates<<<(NN + 63) / 64, 256, 0, stream>>>(
        H0, AGGH, PA + 64, AGGP + 64, 64, 64, 128, 128,
        cstate + (size_t)NN * HD, hstate + (size_t)NN * HD,
        bprep + 65536, wc + 192, bias + 256, NN, wf);
    k_outproj<<<(NN + 7) / 8, 256, 0, stream>>>(PA + 64, Wout, bout,
                                                outs + (size_t)t * NN * OD, NN);
  }
}

// Round 3
// 3903.307 us; speedup vs baseline: 1.9146x; 1.0875x over previous
//
#include <hip/hip_runtime.h>

#define T_STEPS 12
#define NN 100000
#define EE 3200000
#define HD 64
#define OD 32

typedef __attribute__((ext_vector_type(8))) short short8;
typedef __attribute__((ext_vector_type(4))) float f32x4;
typedef unsigned short u16;

__device__ __forceinline__ u16 f2b(float x) {
  union { float f; unsigned u; } v; v.f = x;
  unsigned r = v.u + 0x7FFFu + ((v.u >> 16) & 1u);
  return (u16)(r >> 16);
}
__device__ __forceinline__ float b2f(u16 u) {
  union { unsigned u; float f; } v; v.u = ((unsigned)u) << 16;
  return v.f;
}
__device__ __forceinline__ float sigm(float x) {
  x = fminf(fmaxf(x, -30.f), 30.f);
  return 1.0f / (1.0f + __expf(-x));
}
__device__ __forceinline__ float tanh_f(float x) {
  x = fminf(fmaxf(x, -15.f), 15.f);
  float e = __expf(2.0f * x);
  return (e - 1.0f) / (e + 1.0f);
}

// ---------------- CSR build ----------------
__global__ __launch_bounds__(256) void k_count(const int* __restrict__ dst,
                                               int* __restrict__ deg, int E) {
  int e = blockIdx.x * 256 + threadIdx.x;
  if (e < E) atomicAdd(&deg[dst[e]], 1);
}

// 3-phase multi-block exclusive scan over deg[N]
__global__ __launch_bounds__(1024) void k_scanA(const int* __restrict__ deg,
                                                int* __restrict__ excl,
                                                int* __restrict__ btot, int n) {
  __shared__ int buf[1024];
  int tid = threadIdx.x;
  int i = blockIdx.x * 1024 + tid;
  int v = (i < n) ? deg[i] : 0;
  buf[tid] = v;
  __syncthreads();
  for (int off = 1; off < 1024; off <<= 1) {
    int t = (tid >= off) ? buf[tid - off] : 0;
    __syncthreads();
    buf[tid] += t;
    __syncthreads();
  }
  if (i < n) excl[i] = buf[tid] - v;
  if (tid == 1023) btot[blockIdx.x] = buf[1023];
}

__global__ __launch_bounds__(128) void k_scanB(const int* __restrict__ btot,
                                               int* __restrict__ boffs, int nb) {
  __shared__ int buf[128];
  int tid = threadIdx.x;
  int v = (tid < nb) ? btot[tid] : 0;
  buf[tid] = v;
  __syncthreads();
  for (int off = 1; off < 128; off <<= 1) {
    int t = (tid >= off) ? buf[tid - off] : 0;
    __syncthreads();
    buf[tid] += t;
    __syncthreads();
  }
  if (tid < nb) boffs[tid] = buf[tid] - v;
}

__global__ __launch_bounds__(1024) void k_scanC(const int* __restrict__ deg,
                                                const int* __restrict__ excl,
                                                const int* __restrict__ boffs,
                                                int* __restrict__ row_ptr,
                                                int* __restrict__ cursor,
                                                float* __restrict__ deg_inv, int n) {
  int i = blockIdx.x * 1024 + threadIdx.x;
  if (i < n) {
    int v = excl[i] + boffs[blockIdx.x];
    int d = deg[i];
    row_ptr[i] = v;
    cursor[i] = v;
    deg_inv[i] = d ? (1.0f / (float)d) : 0.0f;
    if (i == n - 1) row_ptr[n] = v + d;
  }
}

__global__ __launch_bounds__(256) void k_scatter(const int* __restrict__ src,
                                                 const int* __restrict__ dst,
                                                 int* __restrict__ cursor,
                                                 int* __restrict__ csr, int E) {
  int e = blockIdx.x * 256 + threadIdx.x;
  if (e < E) {
    int p = atomicAdd(&cursor[dst[e]], 1);
    csr[p] = src[e];
  }
}

// ---------------- weight prep: fragment-ordered bf16 B ----------------
// bprep[l][kb(8)][fi(16)][lane(64)][j(8)] = B[fc][col(fi,lane)]
//   fc  = kb*32 + (lane>>4)*8 + j           (concat-K: [inp|xagg|h|hagg])
//   col: gate g = fi&3, k = (fi>>2)*16 + (lane&15)
__global__ __launch_bounds__(256) void k_prep(const float* __restrict__ Wxs,
                                              const float* __restrict__ Wxn,
                                              const float* __restrict__ Whs,
                                              const float* __restrict__ Whn,
                                              u16* __restrict__ bprep) {
  int idx = blockIdx.x * 256 + threadIdx.x;  // 0..131071
  int l = idx >> 16;
  int kb = (idx >> 13) & 7;
  int fi = (idx >> 9) & 15;
  int ln = (idx >> 3) & 63;
  int j = idx & 7;
  int fc = kb * 32 + ((ln >> 4) << 3) + j;
  int g = fi & 3;
  int kk = ((fi >> 2) << 4) + (ln & 15);
  int t = fc >> 6, f = fc & 63;
  const float* tabs[4] = {Wxs, Wxn, Whs, Whn};
  bprep[idx] = f2b(tabs[t][((size_t)(l * 4 + g) * 64 + f) * 64 + kk]);
}

// Wout prep: wp[kb(2)][fi(2)][lane(64)][j(8)] = Wout[k][o]
//   k = kb*32 + (lane>>4)*8 + j,  o = fi*16 + (lane&15)
__global__ __launch_bounds__(256) void k_prepw(const float* __restrict__ Wout,
                                               u16* __restrict__ wp) {
  int idx = blockIdx.x * 256 + threadIdx.x;  // 0..2047
  int kb = idx >> 10;
  int fi = (idx >> 9) & 1;
  int ln = (idx >> 3) & 63;
  int j = idx & 7;
  int k = kb * 32 + ((ln >> 4) << 3) + j;
  int o = fi * 16 + (ln & 15);
  wp[idx] = f2b(Wout[k * 32 + o]);
}

// ---------------- per-step x -> bf16 into pair buffer ----------------
__global__ __launch_bounds__(256) void k_convx(const float* __restrict__ x,
                                               u16* __restrict__ pa) {
  int idx = blockIdx.x * 256 + threadIdx.x;  // N*8
  int n = idx >> 3, j = idx & 7;
  float4 v0 = *reinterpret_cast<const float4*>(x + (size_t)n * 64 + j * 8);
  float4 v1 = *reinterpret_cast<const float4*>(x + (size_t)n * 64 + j * 8 + 4);
  short8 o;
  o[0] = (short)f2b(v0.x); o[1] = (short)f2b(v0.y);
  o[2] = (short)f2b(v0.z); o[3] = (short)f2b(v0.w);
  o[4] = (short)f2b(v1.x); o[5] = (short)f2b(v1.y);
  o[6] = (short)f2b(v1.z); o[7] = (short)f2b(v1.w);
  *reinterpret_cast<short8*>(pa + (size_t)n * 128 + j * 8) = o;
}

// ---------------- init h (both layers) -> bf16 buffers ----------------
__global__ __launch_bounds__(256) void k_inith(const float* __restrict__ h0,
                                               u16* __restrict__ H0,
                                               u16* __restrict__ PA) {
  int idx = blockIdx.x * 256 + threadIdx.x;  // N*8
  int n = idx >> 3, j = idx & 7;
#pragma unroll
  for (int L = 0; L < 2; ++L) {
    float4 v0 = *reinterpret_cast<const float4*>(h0 + (size_t)L * NN * 64 + (size_t)n * 64 + j * 8);
    float4 v1 = *reinterpret_cast<const float4*>(h0 + (size_t)L * NN * 64 + (size_t)n * 64 + j * 8 + 4);
    short8 o;
    o[0] = (short)f2b(v0.x); o[1] = (short)f2b(v0.y);
    o[2] = (short)f2b(v0.z); o[3] = (short)f2b(v0.w);
    o[4] = (short)f2b(v1.x); o[5] = (short)f2b(v1.y);
    o[6] = (short)f2b(v1.z); o[7] = (short)f2b(v1.w);
    if (L == 0)
      *reinterpret_cast<short8*>(H0 + (size_t)n * 64 + j * 8) = o;
    else
      *reinterpret_cast<short8*>(PA + (size_t)n * 128 + 64 + j * 8) = o;
  }
}

// ---------------- dual mean aggregation over [N][128] bf16 pair ----------------
// 4 edge slots x 16 lanes; 4-deep unrolled gather (16 edges / iter / wave).
__global__ __launch_bounds__(256) void k_agg_pair(const u16* __restrict__ P,
                                                  const int* __restrict__ row_ptr,
                                                  const int* __restrict__ csr,
                                                  const float* __restrict__ deg_inv,
                                                  u16* __restrict__ outp) {
  int node = blockIdx.x * 4 + (threadIdx.x >> 6);
  int lane = threadIdx.x & 63;
  int g = lane >> 4, m = lane & 15;
  int start = row_ptr[node], end = row_ptr[node + 1];
  float a0 = 0, a1 = 0, a2 = 0, a3 = 0, a4 = 0, a5 = 0, a6 = 0, a7 = 0;
  int e = start + g;
  for (; e + 12 < end; e += 16) {
    int s0 = csr[e], s1 = csr[e + 4], s2 = csr[e + 8], s3 = csr[e + 12];
    short8 v0 = *reinterpret_cast<const short8*>(P + (size_t)s0 * 128 + m * 8);
    short8 v1 = *reinterpret_cast<const short8*>(P + (size_t)s1 * 128 + m * 8);
    short8 v2 = *reinterpret_cast<const short8*>(P + (size_t)s2 * 128 + m * 8);
    short8 v3 = *reinterpret_cast<const short8*>(P + (size_t)s3 * 128 + m * 8);
    a0 += (b2f((u16)v0[0]) + b2f((u16)v1[0])) + (b2f((u16)v2[0]) + b2f((u16)v3[0]));
    a1 += (b2f((u16)v0[1]) + b2f((u16)v1[1])) + (b2f((u16)v2[1]) + b2f((u16)v3[1]));
    a2 += (b2f((u16)v0[2]) + b2f((u16)v1[2])) + (b2f((u16)v2[2]) + b2f((u16)v3[2]));
    a3 += (b2f((u16)v0[3]) + b2f((u16)v1[3])) + (b2f((u16)v2[3]) + b2f((u16)v3[3]));
    a4 += (b2f((u16)v0[4]) + b2f((u16)v1[4])) + (b2f((u16)v2[4]) + b2f((u16)v3[4]));
    a5 += (b2f((u16)v0[5]) + b2f((u16)v1[5])) + (b2f((u16)v2[5]) + b2f((u16)v3[5]));
    a6 += (b2f((u16)v0[6]) + b2f((u16)v1[6])) + (b2f((u16)v2[6]) + b2f((u16)v3[6]));
    a7 += (b2f((u16)v0[7]) + b2f((u16)v1[7])) + (b2f((u16)v2[7]) + b2f((u16)v3[7]));
  }
  for (; e < end; e += 4) {
    int s0 = csr[e];
    short8 v0 = *reinterpret_cast<const short8*>(P + (size_t)s0 * 128 + m * 8);
    a0 += b2f((u16)v0[0]); a1 += b2f((u16)v0[1]);
    a2 += b2f((u16)v0[2]); a3 += b2f((u16)v0[3]);
    a4 += b2f((u16)v0[4]); a5 += b2f((u16)v0[5]);
    a6 += b2f((u16)v0[6]); a7 += b2f((u16)v0[7]);
  }
#pragma unroll
  for (int off = 16; off < 64; off <<= 1) {
    a0 += __shfl_xor(a0, off); a1 += __shfl_xor(a1, off);
    a2 += __shfl_xor(a2, off); a3 += __shfl_xor(a3, off);
    a4 += __shfl_xor(a4, off); a5 += __shfl_xor(a5, off);
    a6 += __shfl_xor(a6, off); a7 += __shfl_xor(a7, off);
  }
  if (g == 0) {
    float sc = deg_inv[node];
    short8 o;
    o[0] = (short)f2b(a0 * sc); o[1] = (short)f2b(a1 * sc);
    o[2] = (short)f2b(a2 * sc); o[3] = (short)f2b(a3 * sc);
    o[4] = (short)f2b(a4 * sc); o[5] = (short)f2b(a5 * sc);
    o[6] = (short)f2b(a6 * sc); o[7] = (short)f2b(a7 * sc);
    *reinterpret_cast<short8*>(outp + (size_t)node * 128 + m * 8) = o;
  }
}

// ---------------- single mean aggregation over [N][64] bf16 ----------------
// 8 edge slots x 8 lanes; 4-deep unrolled gather (32 edges / iter / wave).
__global__ __launch_bounds__(256) void k_agg_single(const u16* __restrict__ P,
                                                    const int* __restrict__ row_ptr,
                                                    const int* __restrict__ csr,
                                                    const float* __restrict__ deg_inv,
                                                    u16* __restrict__ outp) {
  int node = blockIdx.x * 4 + (threadIdx.x >> 6);
  int lane = threadIdx.x & 63;
  int g = lane >> 3, m = lane & 7;
  int start = row_ptr[node], end = row_ptr[node + 1];
  float a0 = 0, a1 = 0, a2 = 0, a3 = 0, a4 = 0, a5 = 0, a6 = 0, a7 = 0;
  int e = start + g;
  for (; e + 24 < end; e += 32) {
    int s0 = csr[e], s1 = csr[e + 8], s2 = csr[e + 16], s3 = csr[e + 24];
    short8 v0 = *reinterpret_cast<const short8*>(P + (size_t)s0 * 64 + m * 8);
    short8 v1 = *reinterpret_cast<const short8*>(P + (size_t)s1 * 64 + m * 8);
    short8 v2 = *reinterpret_cast<const short8*>(P + (size_t)s2 * 64 + m * 8);
    short8 v3 = *reinterpret_cast<const short8*>(P + (size_t)s3 * 64 + m * 8);
    a0 += (b2f((u16)v0[0]) + b2f((u16)v1[0])) + (b2f((u16)v2[0]) + b2f((u16)v3[0]));
    a1 += (b2f((u16)v0[1]) + b2f((u16)v1[1])) + (b2f((u16)v2[1]) + b2f((u16)v3[1]));
    a2 += (b2f((u16)v0[2]) + b2f((u16)v1[2])) + (b2f((u16)v2[2]) + b2f((u16)v3[2]));
    a3 += (b2f((u16)v0[3]) + b2f((u16)v1[3])) + (b2f((u16)v2[3]) + b2f((u16)v3[3]));
    a4 += (b2f((u16)v0[4]) + b2f((u16)v1[4])) + (b2f((u16)v2[4]) + b2f((u16)v3[4]));
    a5 += (b2f((u16)v0[5]) + b2f((u16)v1[5])) + (b2f((u16)v2[5]) + b2f((u16)v3[5]));
    a6 += (b2f((u16)v0[6]) + b2f((u16)v1[6])) + (b2f((u16)v2[6]) + b2f((u16)v3[6]));
    a7 += (b2f((u16)v0[7]) + b2f((u16)v1[7])) + (b2f((u16)v2[7]) + b2f((u16)v3[7]));
  }
  for (; e < end; e += 8) {
    int s0 = csr[e];
    short8 v0 = *reinterpret_cast<const short8*>(P + (size_t)s0 * 64 + m * 8);
    a0 += b2f((u16)v0[0]); a1 += b2f((u16)v0[1]);
    a2 += b2f((u16)v0[2]); a3 += b2f((u16)v0[3]);
    a4 += b2f((u16)v0[4]); a5 += b2f((u16)v0[5]);
    a6 += b2f((u16)v0[6]); a7 += b2f((u16)v0[7]);
  }
#pragma unroll
  for (int off = 8; off < 64; off <<= 1) {
    a0 += __shfl_xor(a0, off); a1 += __shfl_xor(a1, off);
    a2 += __shfl_xor(a2, off); a3 += __shfl_xor(a3, off);
    a4 += __shfl_xor(a4, off); a5 += __shfl_xor(a5, off);
    a6 += __shfl_xor(a6, off); a7 += __shfl_xor(a7, off);
  }
  if (g == 0) {
    float sc = deg_inv[node];
    short8 o;
    o[0] = (short)f2b(a0 * sc); o[1] = (short)f2b(a1 * sc);
    o[2] = (short)f2b(a2 * sc); o[3] = (short)f2b(a3 * sc);
    o[4] = (short)f2b(a4 * sc); o[5] = (short)f2b(a5 * sc);
    o[6] = (short)f2b(a6 * sc); o[7] = (short)f2b(a7 * sc);
    *reinterpret_cast<short8*>(outp + (size_t)node * 64 + m * 8) = o;
  }
}

// ---------------- fused gate GEMM + LSTM pointwise (+ optional out-proj) ----
__global__ __launch_bounds__(256, 2) void k_gates(
    const u16* __restrict__ tab0, const u16* __restrict__ tab1,
    u16* __restrict__ tab2, const u16* __restrict__ tab3,
    int ld0, int ld1, int ld2, int ld3,
    float* __restrict__ cst, float* __restrict__ hf32,
    const u16* __restrict__ bprepl,
    const float* __restrict__ wcl, const float* __restrict__ biasl,
    const u16* __restrict__ wproj, const float* __restrict__ boutp,
    float* __restrict__ outp,
    int n_nodes, int writef32, int doproj) {
  __shared__ u16 Hsm[64 * 64];  // 8 KB, used when doproj
  const int tid = threadIdx.x;
  const int lane = tid & 63;
  const int w = tid >> 6;
  const int nb = blockIdx.x * 64;
  const int cl = lane & 15;
  const int kg = lane >> 4;

  short8 breg[8][4];
#pragma unroll
  for (int kb = 0; kb < 8; ++kb)
#pragma unroll
    for (int fl = 0; fl < 4; ++fl)
      breg[kb][fl] = *reinterpret_cast<const short8*>(
          bprepl + (kb << 13) + (((w << 2) + fl) << 9) + (lane << 3));

  const u16* tabs[4] = {tab0, tab1, tab2, tab3};
  const int lds[4] = {ld0, ld1, ld2, ld3};
  int gnc[4];
#pragma unroll
  for (int rg = 0; rg < 4; ++rg) {
    int g = nb + rg * 16 + cl;
    gnc[rg] = (g < n_nodes) ? g : (n_nodes - 1);
  }

  f32x4 acc[4][4];
  f32x4 z4 = {0.f, 0.f, 0.f, 0.f};
#pragma unroll
  for (int a = 0; a < 4; ++a)
#pragma unroll
    for (int b = 0; b < 4; ++b) acc[a][b] = z4;

  const int koff = kg << 3;
#pragma unroll
  for (int kb = 0; kb < 8; ++kb) {
    const u16* tp = tabs[kb >> 1];
    const int ld = lds[kb >> 1];
    const int idx = ((kb & 1) << 5) + koff;
#pragma unroll
    for (int rg = 0; rg < 4; ++rg) {
      short8 a = *reinterpret_cast<const short8*>(tp + (size_t)gnc[rg] * ld + idx);
      acc[rg][0] = __builtin_amdgcn_mfma_f32_16x16x32_bf16(a, breg[kb][0], acc[rg][0], 0, 0, 0);
      acc[rg][1] = __builtin_amdgcn_mfma_f32_16x16x32_bf16(a, breg[kb][1], acc[rg][1], 0, 0, 0);
      acc[rg][2] = __builtin_amdgcn_mfma_f32_16x16x32_bf16(a, breg[kb][2], acc[rg][2], 0, 0, 0);
      acc[rg][3] = __builtin_amdgcn_mfma_f32_16x16x32_bf16(a, breg[kb][3], acc[rg][3], 0, 0, 0);
    }
  }

  const int k = (w << 4) + cl;
  const float wci = wcl[k], wcf = wcl[64 + k], wco = wcl[128 + k];
  const float bi = biasl[k], bfg = biasl[64 + k], bc = biasl[128 + k], bo = biasl[192 + k];
#pragma unroll
  for (int rg = 0; rg < 4; ++rg) {
#pragma unroll
    for (int r = 0; r < 4; ++r) {
      int n = nb + rg * 16 + kg * 4 + r;
      if (n < n_nodes) {
        size_t off = (size_t)n * 64 + k;
        float c_old = cst[off];
        float ig = sigm(acc[rg][0][r] + wci * c_old + bi);
        float fg = sigm(acc[rg][1][r] + wcf * c_old + bfg);
        float ct = tanh_f(acc[rg][2][r] + bc);
        float nc = fg * c_old + ig * ct;
        float og = sigm(acc[rg][3][r] + wco * nc + bo);
        float nh = og * tanh_f(nc);
        cst[off] = nc;
        u16 hb = f2b(nh);
        tab2[(size_t)n * ld2 + k] = hb;
        if (doproj) Hsm[(rg * 16 + kg * 4 + r) * 64 + k] = hb;
        if (writef32) hf32[off] = nh;
      }
    }
  }

  if (doproj) {
    __syncthreads();
    // P = H(64x64) @ Wout(64x32); wave w does its 16-node row tile.
    short8 bw[2][2];
#pragma unroll
    for (int kb = 0; kb < 2; ++kb)
#pragma unroll
      for (int fi = 0; fi < 2; ++fi)
        bw[kb][fi] = *reinterpret_cast<const short8*>(wproj + (((kb * 2 + fi) * 64 + lane) << 3));
    short8 a0 = *reinterpret_cast<const short8*>(&Hsm[(w * 16 + cl) * 64 + kg * 8]);
    short8 a1 = *reinterpret_cast<const short8*>(&Hsm[(w * 16 + cl) * 64 + 32 + kg * 8]);
    f32x4 p0 = z4, p1 = z4;
    p0 = __builtin_amdgcn_mfma_f32_16x16x32_bf16(a0, bw[0][0], p0, 0, 0, 0);
    p0 = __builtin_amdgcn_mfma_f32_16x16x32_bf16(a1, bw[1][0], p0, 0, 0, 0);
    p1 = __builtin_amdgcn_mfma_f32_16x16x32_bf16(a0, bw[0][1], p1, 0, 0, 0);
    p1 = __builtin_amdgcn_mfma_f32_16x16x32_bf16(a1, bw[1][1], p1, 0, 0, 0);
    const float bo0 = boutp[cl], bo1 = boutp[16 + cl];
#pragma unroll
    for (int r = 0; r < 4; ++r) {
      int n = nb + w * 16 + kg * 4 + r;
      if (n < n_nodes) {
        outp[(size_t)n * OD + cl] = p0[r] + bo0;
        outp[(size_t)n * OD + 16 + cl] = p1[r] + bo1;
      }
    }
  }
}

extern "C" void kernel_launch(void* const* d_in, const int* in_sizes, int n_in,
                              void* d_out, int out_size, void* d_ws, size_t ws_size,
                              hipStream_t stream) {
  const float* x = (const float*)d_in[0];
  const float* h0 = (const float*)d_in[1];
  const float* c0 = (const float*)d_in[2];
  const float* Wxs = (const float*)d_in[3];
  const float* Wxn = (const float*)d_in[4];
  const float* Whs = (const float*)d_in[5];
  const float* Whn = (const float*)d_in[6];
  const float* wc = (const float*)d_in[7];
  const float* bias = (const float*)d_in[8];
  const float* Wout = (const float*)d_in[9];
  const float* bout = (const float*)d_in[10];
  const int* src = (const int*)d_in[11];
  const int* dst = (const int*)d_in[12];

  float* out = (float*)d_out;
  float* outs = out;                                   // [T][N][O]
  float* hstate = out + (size_t)T_STEPS * NN * OD;     // [2][N][64] fp32 (final)
  float* cstate = hstate + (size_t)2 * NN * HD;        // [2][N][64] fp32 (live)

  char* p = (char*)d_ws;
  auto alloc = [&](size_t bytes) {
    char* r = p;
    p += (bytes + 255) & ~(size_t)255;
    return r;
  };
  int* csr = (int*)alloc((size_t)EE * 4);
  int* row_ptr = (int*)alloc((size_t)(NN + 1) * 4);
  int* cursor = (int*)alloc((size_t)NN * 4);
  int* deg = (int*)alloc((size_t)NN * 4);
  int* excl = (int*)alloc((size_t)NN * 4);
  int* btot = (int*)alloc(128 * 4);
  int* boffs = (int*)alloc(128 * 4);
  float* deg_inv = (float*)alloc((size_t)NN * 4);
  u16* PA = (u16*)alloc((size_t)NN * 128 * 2);    // [x_t | h_l1] bf16
  u16* H0 = (u16*)alloc((size_t)NN * 64 * 2);     // h_l0 bf16
  u16* AGGP = (u16*)alloc((size_t)NN * 128 * 2);  // [agg(x) | agg(h_l1)]
  u16* AGGH = (u16*)alloc((size_t)NN * 64 * 2);   // agg(h_l0) cached across steps
  u16* bprep = (u16*)alloc((size_t)2 * 65536 * 2);
  u16* wprep = (u16*)alloc((size_t)2048 * 2);

  const int nscan = (NN + 1023) / 1024;  // 98

  // prologue: CSR build + weight prep + state init
  hipMemsetAsync(deg, 0, (size_t)NN * 4, stream);
  k_count<<<EE / 256, 256, 0, stream>>>(dst, deg, EE);
  k_scanA<<<nscan, 1024, 0, stream>>>(deg, excl, btot, NN);
  k_scanB<<<1, 128, 0, stream>>>(btot, boffs, nscan);
  k_scanC<<<nscan, 1024, 0, stream>>>(deg, excl, boffs, row_ptr, cursor, deg_inv, NN);
  k_scatter<<<EE / 256, 256, 0, stream>>>(src, dst, cursor, csr, EE);
  k_prep<<<512, 256, 0, stream>>>(Wxs, Wxn, Whs, Whn, bprep);
  k_prepw<<<8, 256, 0, stream>>>(Wout, wprep);
  k_inith<<<NN * 8 / 256, 256, 0, stream>>>(h0, H0, PA);
  hipMemcpyAsync(cstate, c0, (size_t)2 * NN * HD * 4, hipMemcpyDeviceToDevice, stream);
  k_agg_single<<<NN / 4, 256, 0, stream>>>(H0, row_ptr, csr, deg_inv, AGGH);

  for (int t = 0; t < T_STEPS; ++t) {
    int wf = (t == T_STEPS - 1) ? 1 : 0;
    k_convx<<<NN * 8 / 256, 256, 0, stream>>>(x + (size_t)t * NN * HD, PA);
    // dual agg: mean(x_t) and mean(h_l1_old)
    k_agg_pair<<<NN / 4, 256, 0, stream>>>(PA, row_ptr, csr, deg_inv, AGGP);
    // layer 0: inp=x_t(PA,0), xagg=AGGP(0), h=H0 (in-place), hagg=AGGH (cached)
    k_gates<<<(NN + 63) / 64, 256, 0, stream>>>(
        PA, AGGP, H0, AGGH, 128, 128, 64, 64,
        cstate, hstate, bprep, wc, bias,
        wprep, bout, nullptr, NN, wf, 0);
    // agg of new h_l0: layer-1 x-side now AND layer-0 h-side next step
    k_agg_single<<<NN / 4, 256, 0, stream>>>(H0, row_ptr, csr, deg_inv, AGGH);
    // layer 1 (+ fused out-proj): inp=H0, xagg=AGGH, h=PA+64, hagg=AGGP+64
    k_gates<<<(NN + 63) / 64, 256, 0, stream>>>(
        H0, AGGH, PA + 64, AGGP + 64, 64, 64, 128, 128,
        cstate + (size_t)NN * HD, hstate + (size_t)NN * HD,
        bprep + 65536, wc + 192, bias + 256,
        wprep, bout, outs + (size_t)t * NN * OD, NN, wf, 1);
  }
}

// Round 4
// 3687.300 us; speedup vs baseline: 2.0268x; 1.0586x over previous
//
#include <hip/hip_runtime.h>

#define T_STEPS 12
#define NN 100000
#define EE 3200000
#define HD 64
#define OD 32
#define NBK 391  // (NN+255)/256 buckets of 256 nodes

typedef __attribute__((ext_vector_type(8))) short short8;
typedef __attribute__((ext_vector_type(4))) float f32x4;
typedef unsigned short u16;

__device__ __forceinline__ u16 f2b(float x) {
  union { float f; unsigned u; } v; v.f = x;
  unsigned r = v.u + 0x7FFFu + ((v.u >> 16) & 1u);
  return (u16)(r >> 16);
}
__device__ __forceinline__ float b2f(u16 u) {
  union { unsigned u; float f; } v; v.u = ((unsigned)u) << 16;
  return v.f;
}
__device__ __forceinline__ float sigm(float x) {
  x = fminf(fmaxf(x, -30.f), 30.f);
  return 1.0f / (1.0f + __expf(-x));
}
__device__ __forceinline__ float tanh_f(float x) {
  x = fminf(fmaxf(x, -15.f), 15.f);
  float e = __expf(2.0f * x);
  return (e - 1.0f) / (e + 1.0f);
}

// ================= bucketed CSR build =================
// Pass A: per-block LDS histogram of dst>>8 -> global bucket counts
__global__ __launch_bounds__(256) void k_bhist(const int* __restrict__ dst,
                                               int* __restrict__ bcnt, int E) {
  __shared__ int h[NBK];
  for (int i = threadIdx.x; i < NBK; i += 256) h[i] = 0;
  __syncthreads();
  int base = blockIdx.x * 4096;
#pragma unroll
  for (int i = 0; i < 16; ++i) {
    int e = base + i * 256 + threadIdx.x;
    if (e < E) atomicAdd(&h[dst[e] >> 8], 1);
  }
  __syncthreads();
  for (int i = threadIdx.x; i < NBK; i += 256)
    if (h[i]) atomicAdd(&bcnt[i], h[i]);
}

__global__ __launch_bounds__(512) void k_bscan(const int* __restrict__ bcnt,
                                               int* __restrict__ bcur) {
  __shared__ int buf[512];
  int tid = threadIdx.x;
  int v = (tid < NBK) ? bcnt[tid] : 0;
  buf[tid] = v;
  __syncthreads();
  for (int off = 1; off < 512; off <<= 1) {
    int t = (tid >= off) ? buf[tid - off] : 0;
    __syncthreads();
    buf[tid] += t;
    __syncthreads();
  }
  if (tid < NBK) bcur[tid] = buf[tid] - v;
}

// Pass B: write (src,dst) into bucket-sorted array via block reservations
__global__ __launch_bounds__(256) void k_bscatter(const int* __restrict__ src,
                                                  const int* __restrict__ dst,
                                                  int* __restrict__ bcur,
                                                  uint2* __restrict__ binned, int E) {
  __shared__ int h[NBK];
  __shared__ int base[NBK];
  __shared__ int cur[NBK];
  for (int i = threadIdx.x; i < NBK; i += 256) { h[i] = 0; cur[i] = 0; }
  __syncthreads();
  int b0 = blockIdx.x * 4096;
  int d[16], s[16];
#pragma unroll
  for (int i = 0; i < 16; ++i) {
    int e = b0 + i * 256 + threadIdx.x;
    if (e < E) {
      d[i] = dst[e];
      s[i] = src[e];
      atomicAdd(&h[d[i] >> 8], 1);
    } else d[i] = -1;
  }
  __syncthreads();
  for (int i = threadIdx.x; i < NBK; i += 256)
    if (h[i]) base[i] = atomicAdd(&bcur[i], h[i]);
  __syncthreads();
#pragma unroll
  for (int i = 0; i < 16; ++i) {
    if (d[i] >= 0) {
      int bk = d[i] >> 8;
      int r = atomicAdd(&cur[bk], 1);
      binned[base[bk] + r] = make_uint2((unsigned)s[i], (unsigned)d[i]);
    }
  }
}

// degree count over bucket-sorted edges (localized atomics)
__global__ __launch_bounds__(256) void k_count2(const uint2* __restrict__ binned,
                                                int* __restrict__ deg, int E) {
  int e = blockIdx.x * 256 + threadIdx.x;
  if (e < E) atomicAdd(&deg[binned[e].y], 1);
}

// 3-phase multi-block exclusive scan over deg[N]
__global__ __launch_bounds__(1024) void k_scanA(const int* __restrict__ deg,
                                                int* __restrict__ excl,
                                                int* __restrict__ btot, int n) {
  __shared__ int buf[1024];
  int tid = threadIdx.x;
  int i = blockIdx.x * 1024 + tid;
  int v = (i < n) ? deg[i] : 0;
  buf[tid] = v;
  __syncthreads();
  for (int off = 1; off < 1024; off <<= 1) {
    int t = (tid >= off) ? buf[tid - off] : 0;
    __syncthreads();
    buf[tid] += t;
    __syncthreads();
  }
  if (i < n) excl[i] = buf[tid] - v;
  if (tid == 1023) btot[blockIdx.x] = buf[1023];
}

__global__ __launch_bounds__(128) void k_scanB(const int* __restrict__ btot,
                                               int* __restrict__ boffs, int nb) {
  __shared__ int buf[128];
  int tid = threadIdx.x;
  int v = (tid < nb) ? btot[tid] : 0;
  buf[tid] = v;
  __syncthreads();
  for (int off = 1; off < 128; off <<= 1) {
    int t = (tid >= off) ? buf[tid - off] : 0;
    __syncthreads();
    buf[tid] += t;
    __syncthreads();
  }
  if (tid < nb) boffs[tid] = buf[tid] - v;
}

__global__ __launch_bounds__(1024) void k_scanC(const int* __restrict__ deg,
                                                const int* __restrict__ excl,
                                                const int* __restrict__ boffs,
                                                int* __restrict__ row_ptr,
                                                int* __restrict__ cursor,
                                                float* __restrict__ deg_inv, int n) {
  int i = blockIdx.x * 1024 + threadIdx.x;
  if (i < n) {
    int v = excl[i] + boffs[blockIdx.x];
    int d = deg[i];
    row_ptr[i] = v;
    cursor[i] = v;
    deg_inv[i] = d ? (1.0f / (float)d) : 0.0f;
    if (i == n - 1) row_ptr[n] = v + d;
  }
}

// final scatter over bucket-sorted edges: cursor + csr writes are localized
__global__ __launch_bounds__(256) void k_scatter2(const uint2* __restrict__ binned,
                                                  int* __restrict__ cursor,
                                                  int* __restrict__ csr, int E) {
  int e = blockIdx.x * 256 + threadIdx.x;
  if (e < E) {
    uint2 p = binned[e];
    int pos = atomicAdd(&cursor[p.y], 1);
    csr[pos] = (int)p.x;
  }
}

// ---------------- weight prep: fragment-ordered bf16 B ----------------
__global__ __launch_bounds__(256) void k_prep(const float* __restrict__ Wxs,
                                              const float* __restrict__ Wxn,
                                              const float* __restrict__ Whs,
                                              const float* __restrict__ Whn,
                                              u16* __restrict__ bprep) {
  int idx = blockIdx.x * 256 + threadIdx.x;  // 0..131071
  int l = idx >> 16;
  int kb = (idx >> 13) & 7;
  int fi = (idx >> 9) & 15;
  int ln = (idx >> 3) & 63;
  int j = idx & 7;
  int fc = kb * 32 + ((ln >> 4) << 3) + j;
  int g = fi & 3;
  int kk = ((fi >> 2) << 4) + (ln & 15);
  int t = fc >> 6, f = fc & 63;
  const float* tabs[4] = {Wxs, Wxn, Whs, Whn};
  bprep[idx] = f2b(tabs[t][((size_t)(l * 4 + g) * 64 + f) * 64 + kk]);
}

__global__ __launch_bounds__(256) void k_prepw(const float* __restrict__ Wout,
                                               u16* __restrict__ wp) {
  int idx = blockIdx.x * 256 + threadIdx.x;  // 0..2047
  int kb = idx >> 10;
  int fi = (idx >> 9) & 1;
  int ln = (idx >> 3) & 63;
  int j = idx & 7;
  int k = kb * 32 + ((ln >> 4) << 3) + j;
  int o = fi * 16 + (ln & 15);
  wp[idx] = f2b(Wout[k * 32 + o]);
}

// ---------------- per-step x -> bf16 into pair buffer ----------------
__global__ __launch_bounds__(256) void k_convx(const float* __restrict__ x,
                                               u16* __restrict__ pa) {
  int idx = blockIdx.x * 256 + threadIdx.x;  // N*8
  int n = idx >> 3, j = idx & 7;
  float4 v0 = *reinterpret_cast<const float4*>(x + (size_t)n * 64 + j * 8);
  float4 v1 = *reinterpret_cast<const float4*>(x + (size_t)n * 64 + j * 8 + 4);
  short8 o;
  o[0] = (short)f2b(v0.x); o[1] = (short)f2b(v0.y);
  o[2] = (short)f2b(v0.z); o[3] = (short)f2b(v0.w);
  o[4] = (short)f2b(v1.x); o[5] = (short)f2b(v1.y);
  o[6] = (short)f2b(v1.z); o[7] = (short)f2b(v1.w);
  *reinterpret_cast<short8*>(pa + (size_t)n * 128 + j * 8) = o;
}

// ---------------- init h (both layers) -> bf16 buffers ----------------
__global__ __launch_bounds__(256) void k_inith(const float* __restrict__ h0,
                                               u16* __restrict__ H0,
                                               u16* __restrict__ PA) {
  int idx = blockIdx.x * 256 + threadIdx.x;  // N*8
  int n = idx >> 3, j = idx & 7;
#pragma unroll
  for (int L = 0; L < 2; ++L) {
    float4 v0 = *reinterpret_cast<const float4*>(h0 + (size_t)L * NN * 64 + (size_t)n * 64 + j * 8);
    float4 v1 = *reinterpret_cast<const float4*>(h0 + (size_t)L * NN * 64 + (size_t)n * 64 + j * 8 + 4);
    short8 o;
    o[0] = (short)f2b(v0.x); o[1] = (short)f2b(v0.y);
    o[2] = (short)f2b(v0.z); o[3] = (short)f2b(v0.w);
    o[4] = (short)f2b(v1.x); o[5] = (short)f2b(v1.y);
    o[6] = (short)f2b(v1.z); o[7] = (short)f2b(v1.w);
    if (L == 0)
      *reinterpret_cast<short8*>(H0 + (size_t)n * 64 + j * 8) = o;
    else
      *reinterpret_cast<short8*>(PA + (size_t)n * 128 + 64 + j * 8) = o;
  }
}

// ---------------- dual mean aggregation over [N][128] bf16 pair ----------------
// 4 edge slots x 16 lanes; depth-4 main loop, depth-2/1 tail.
__global__ __launch_bounds__(256) void k_agg_pair(const u16* __restrict__ P,
                                                  const int* __restrict__ row_ptr,
                                                  const int* __restrict__ csr,
                                                  const float* __restrict__ deg_inv,
                                                  u16* __restrict__ outp) {
  int node = blockIdx.x * 4 + (threadIdx.x >> 6);
  int lane = threadIdx.x & 63;
  int g = lane >> 4, m = lane & 15;
  int start = row_ptr[node], end = row_ptr[node + 1];
  float a0 = 0, a1 = 0, a2 = 0, a3 = 0, a4 = 0, a5 = 0, a6 = 0, a7 = 0;
  int e = start + g;
  for (; e + 12 < end; e += 16) {
    int s0 = csr[e], s1 = csr[e + 4], s2 = csr[e + 8], s3 = csr[e + 12];
    short8 v0 = *reinterpret_cast<const short8*>(P + (size_t)s0 * 128 + m * 8);
    short8 v1 = *reinterpret_cast<const short8*>(P + (size_t)s1 * 128 + m * 8);
    short8 v2 = *reinterpret_cast<const short8*>(P + (size_t)s2 * 128 + m * 8);
    short8 v3 = *reinterpret_cast<const short8*>(P + (size_t)s3 * 128 + m * 8);
    a0 += (b2f((u16)v0[0]) + b2f((u16)v1[0])) + (b2f((u16)v2[0]) + b2f((u16)v3[0]));
    a1 += (b2f((u16)v0[1]) + b2f((u16)v1[1])) + (b2f((u16)v2[1]) + b2f((u16)v3[1]));
    a2 += (b2f((u16)v0[2]) + b2f((u16)v1[2])) + (b2f((u16)v2[2]) + b2f((u16)v3[2]));
    a3 += (b2f((u16)v0[3]) + b2f((u16)v1[3])) + (b2f((u16)v2[3]) + b2f((u16)v3[3]));
    a4 += (b2f((u16)v0[4]) + b2f((u16)v1[4])) + (b2f((u16)v2[4]) + b2f((u16)v3[4]));
    a5 += (b2f((u16)v0[5]) + b2f((u16)v1[5])) + (b2f((u16)v2[5]) + b2f((u16)v3[5]));
    a6 += (b2f((u16)v0[6]) + b2f((u16)v1[6])) + (b2f((u16)v2[6]) + b2f((u16)v3[6]));
    a7 += (b2f((u16)v0[7]) + b2f((u16)v1[7])) + (b2f((u16)v2[7]) + b2f((u16)v3[7]));
  }
  if (e + 4 < end) {
    int s0 = csr[e], s1 = csr[e + 4];
    short8 v0 = *reinterpret_cast<const short8*>(P + (size_t)s0 * 128 + m * 8);
    short8 v1 = *reinterpret_cast<const short8*>(P + (size_t)s1 * 128 + m * 8);
    a0 += b2f((u16)v0[0]) + b2f((u16)v1[0]);
    a1 += b2f((u16)v0[1]) + b2f((u16)v1[1]);
    a2 += b2f((u16)v0[2]) + b2f((u16)v1[2]);
    a3 += b2f((u16)v0[3]) + b2f((u16)v1[3]);
    a4 += b2f((u16)v0[4]) + b2f((u16)v1[4]);
    a5 += b2f((u16)v0[5]) + b2f((u16)v1[5]);
    a6 += b2f((u16)v0[6]) + b2f((u16)v1[6]);
    a7 += b2f((u16)v0[7]) + b2f((u16)v1[7]);
    e += 8;
  }
  if (e < end) {
    int s0 = csr[e];
    short8 v0 = *reinterpret_cast<const short8*>(P + (size_t)s0 * 128 + m * 8);
    a0 += b2f((u16)v0[0]); a1 += b2f((u16)v0[1]);
    a2 += b2f((u16)v0[2]); a3 += b2f((u16)v0[3]);
    a4 += b2f((u16)v0[4]); a5 += b2f((u16)v0[5]);
    a6 += b2f((u16)v0[6]); a7 += b2f((u16)v0[7]);
  }
#pragma unroll
  for (int off = 16; off < 64; off <<= 1) {
    a0 += __shfl_xor(a0, off); a1 += __shfl_xor(a1, off);
    a2 += __shfl_xor(a2, off); a3 += __shfl_xor(a3, off);
    a4 += __shfl_xor(a4, off); a5 += __shfl_xor(a5, off);
    a6 += __shfl_xor(a6, off); a7 += __shfl_xor(a7, off);
  }
  if (g == 0) {
    float sc = deg_inv[node];
    short8 o;
    o[0] = (short)f2b(a0 * sc); o[1] = (short)f2b(a1 * sc);
    o[2] = (short)f2b(a2 * sc); o[3] = (short)f2b(a3 * sc);
    o[4] = (short)f2b(a4 * sc); o[5] = (short)f2b(a5 * sc);
    o[6] = (short)f2b(a6 * sc); o[7] = (short)f2b(a7 * sc);
    *reinterpret_cast<short8*>(outp + (size_t)node * 128 + m * 8) = o;
  }
}

// ---------------- single mean aggregation over [N][64] bf16 ----------------
// 8 edge slots x 8 lanes; depth-4 main loop, depth-2/1 tail.
__global__ __launch_bounds__(256) void k_agg_single(const u16* __restrict__ P,
                                                    const int* __restrict__ row_ptr,
                                                    const int* __restrict__ csr,
                                                    const float* __restrict__ deg_inv,
                                                    u16* __restrict__ outp) {
  int node = blockIdx.x * 4 + (threadIdx.x >> 6);
  int lane = threadIdx.x & 63;
  int g = lane >> 3, m = lane & 7;
  int start = row_ptr[node], end = row_ptr[node + 1];
  float a0 = 0, a1 = 0, a2 = 0, a3 = 0, a4 = 0, a5 = 0, a6 = 0, a7 = 0;
  int e = start + g;
  for (; e + 24 < end; e += 32) {
    int s0 = csr[e], s1 = csr[e + 8], s2 = csr[e + 16], s3 = csr[e + 24];
    short8 v0 = *reinterpret_cast<const short8*>(P + (size_t)s0 * 64 + m * 8);
    short8 v1 = *reinterpret_cast<const short8*>(P + (size_t)s1 * 64 + m * 8);
    short8 v2 = *reinterpret_cast<const short8*>(P + (size_t)s2 * 64 + m * 8);
    short8 v3 = *reinterpret_cast<const short8*>(P + (size_t)s3 * 64 + m * 8);
    a0 += (b2f((u16)v0[0]) + b2f((u16)v1[0])) + (b2f((u16)v2[0]) + b2f((u16)v3[0]));
    a1 += (b2f((u16)v0[1]) + b2f((u16)v1[1])) + (b2f((u16)v2[1]) + b2f((u16)v3[1]));
    a2 += (b2f((u16)v0[2]) + b2f((u16)v1[2])) + (b2f((u16)v2[2]) + b2f((u16)v3[2]));
    a3 += (b2f((u16)v0[3]) + b2f((u16)v1[3])) + (b2f((u16)v2[3]) + b2f((u16)v3[3]));
    a4 += (b2f((u16)v0[4]) + b2f((u16)v1[4])) + (b2f((u16)v2[4]) + b2f((u16)v3[4]));
    a5 += (b2f((u16)v0[5]) + b2f((u16)v1[5])) + (b2f((u16)v2[5]) + b2f((u16)v3[5]));
    a6 += (b2f((u16)v0[6]) + b2f((u16)v1[6])) + (b2f((u16)v2[6]) + b2f((u16)v3[6]));
    a7 += (b2f((u16)v0[7]) + b2f((u16)v1[7])) + (b2f((u16)v2[7]) + b2f((u16)v3[7]));
  }
  if (e + 8 < end) {
    int s0 = csr[e], s1 = csr[e + 8];
    short8 v0 = *reinterpret_cast<const short8*>(P + (size_t)s0 * 64 + m * 8);
    short8 v1 = *reinterpret_cast<const short8*>(P + (size_t)s1 * 64 + m * 8);
    a0 += b2f((u16)v0[0]) + b2f((u16)v1[0]);
    a1 += b2f((u16)v0[1]) + b2f((u16)v1[1]);
    a2 += b2f((u16)v0[2]) + b2f((u16)v1[2]);
    a3 += b2f((u16)v0[3]) + b2f((u16)v1[3]);
    a4 += b2f((u16)v0[4]) + b2f((u16)v1[4]);
    a5 += b2f((u16)v0[5]) + b2f((u16)v1[5]);
    a6 += b2f((u16)v0[6]) + b2f((u16)v1[6]);
    a7 += b2f((u16)v0[7]) + b2f((u16)v1[7]);
    e += 16;
  }
  if (e < end) {
    int s0 = csr[e];
    short8 v0 = *reinterpret_cast<const short8*>(P + (size_t)s0 * 64 + m * 8);
    a0 += b2f((u16)v0[0]); a1 += b2f((u16)v0[1]);
    a2 += b2f((u16)v0[2]); a3 += b2f((u16)v0[3]);
    a4 += b2f((u16)v0[4]); a5 += b2f((u16)v0[5]);
    a6 += b2f((u16)v0[6]); a7 += b2f((u16)v0[7]);
  }
#pragma unroll
  for (int off = 8; off < 64; off <<= 1) {
    a0 += __shfl_xor(a0, off); a1 += __shfl_xor(a1, off);
    a2 += __shfl_xor(a2, off); a3 += __shfl_xor(a3, off);
    a4 += __shfl_xor(a4, off); a5 += __shfl_xor(a5, off);
    a6 += __shfl_xor(a6, off); a7 += __shfl_xor(a7, off);
  }
  if (g == 0) {
    float sc = deg_inv[node];
    short8 o;
    o[0] = (short)f2b(a0 * sc); o[1] = (short)f2b(a1 * sc);
    o[2] = (short)f2b(a2 * sc); o[3] = (short)f2b(a3 * sc);
    o[4] = (short)f2b(a4 * sc); o[5] = (short)f2b(a5 * sc);
    o[6] = (short)f2b(a6 * sc); o[7] = (short)f2b(a7 * sc);
    *reinterpret_cast<short8*>(outp + (size_t)node * 64 + m * 8) = o;
  }
}

// ---------------- fused gate GEMM + LSTM pointwise (+ optional out-proj) ----
__global__ __launch_bounds__(256, 2) void k_gates(
    const u16* __restrict__ tab0, const u16* __restrict__ tab1,
    u16* __restrict__ tab2, const u16* __restrict__ tab3,
    int ld0, int ld1, int ld2, int ld3,
    float* __restrict__ cst, float* __restrict__ hf32,
    const u16* __restrict__ bprepl,
    const float* __restrict__ wcl, const float* __restrict__ biasl,
    const u16* __restrict__ wproj, const float* __restrict__ boutp,
    float* __restrict__ outp,
    int n_nodes, int writef32, int doproj) {
  __shared__ u16 Hsm[64 * 64];  // 8 KB, used when doproj
  const int tid = threadIdx.x;
  const int lane = tid & 63;
  const int w = tid >> 6;
  const int nb = blockIdx.x * 64;
  const int cl = lane & 15;
  const int kg = lane >> 4;

  short8 breg[8][4];
#pragma unroll
  for (int kb = 0; kb < 8; ++kb)
#pragma unroll
    for (int fl = 0; fl < 4; ++fl)
      breg[kb][fl] = *reinterpret_cast<const short8*>(
          bprepl + (kb << 13) + (((w << 2) + fl) << 9) + (lane << 3));

  const u16* tabs[4] = {tab0, tab1, tab2, tab3};
  const int lds[4] = {ld0, ld1, ld2, ld3};
  int gnc[4];
#pragma unroll
  for (int rg = 0; rg < 4; ++rg) {
    int g = nb + rg * 16 + cl;
    gnc[rg] = (g < n_nodes) ? g : (n_nodes - 1);
  }

  f32x4 acc[4][4];
  f32x4 z4 = {0.f, 0.f, 0.f, 0.f};
#pragma unroll
  for (int a = 0; a < 4; ++a)
#pragma unroll
    for (int b = 0; b < 4; ++b) acc[a][b] = z4;

  const int koff = kg << 3;
#pragma unroll
  for (int kb = 0; kb < 8; ++kb) {
    const u16* tp = tabs[kb >> 1];
    const int ld = lds[kb >> 1];
    const int idx = ((kb & 1) << 5) + koff;
#pragma unroll
    for (int rg = 0; rg < 4; ++rg) {
      short8 a = *reinterpret_cast<const short8*>(tp + (size_t)gnc[rg] * ld + idx);
      acc[rg][0] = __builtin_amdgcn_mfma_f32_16x16x32_bf16(a, breg[kb][0], acc[rg][0], 0, 0, 0);
      acc[rg][1] = __builtin_amdgcn_mfma_f32_16x16x32_bf16(a, breg[kb][1], acc[rg][1], 0, 0, 0);
      acc[rg][2] = __builtin_amdgcn_mfma_f32_16x16x32_bf16(a, breg[kb][2], acc[rg][2], 0, 0, 0);
      acc[rg][3] = __builtin_amdgcn_mfma_f32_16x16x32_bf16(a, breg[kb][3], acc[rg][3], 0, 0, 0);
    }
  }

  const int k = (w << 4) + cl;
  const float wci = wcl[k], wcf = wcl[64 + k], wco = wcl[128 + k];
  const float bi = biasl[k], bfg = biasl[64 + k], bc = biasl[128 + k], bo = biasl[192 + k];
#pragma unroll
  for (int rg = 0; rg < 4; ++rg) {
#pragma unroll
    for (int r = 0; r < 4; ++r) {
      int n = nb + rg * 16 + kg * 4 + r;
      if (n < n_nodes) {
        size_t off = (size_t)n * 64 + k;
        float c_old = cst[off];
        float ig = sigm(acc[rg][0][r] + wci * c_old + bi);
        float fg = sigm(acc[rg][1][r] + wcf * c_old + bfg);
        float ct = tanh_f(acc[rg][2][r] + bc);
        float nc = fg * c_old + ig * ct;
        float og = sigm(acc[rg][3][r] + wco * nc + bo);
        float nh = og * tanh_f(nc);
        cst[off] = nc;
        u16 hb = f2b(nh);
        tab2[(size_t)n * ld2 + k] = hb;
        if (doproj) Hsm[(rg * 16 + kg * 4 + r) * 64 + k] = hb;
        if (writef32) hf32[off] = nh;
      }
    }
  }

  if (doproj) {
    __syncthreads();
    short8 bw[2][2];
#pragma unroll
    for (int kb = 0; kb < 2; ++kb)
#pragma unroll
      for (int fi = 0; fi < 2; ++fi)
        bw[kb][fi] = *reinterpret_cast<const short8*>(wproj + (((kb * 2 + fi) * 64 + lane) << 3));
    short8 a0 = *reinterpret_cast<const short8*>(&Hsm[(w * 16 + cl) * 64 + kg * 8]);
    short8 a1 = *reinterpret_cast<const short8*>(&Hsm[(w * 16 + cl) * 64 + 32 + kg * 8]);
    f32x4 p0 = z4, p1 = z4;
    p0 = __builtin_amdgcn_mfma_f32_16x16x32_bf16(a0, bw[0][0], p0, 0, 0, 0);
    p0 = __builtin_amdgcn_mfma_f32_16x16x32_bf16(a1, bw[1][0], p0, 0, 0, 0);
    p1 = __builtin_amdgcn_mfma_f32_16x16x32_bf16(a0, bw[0][1], p1, 0, 0, 0);
    p1 = __builtin_amdgcn_mfma_f32_16x16x32_bf16(a1, bw[1][1], p1, 0, 0, 0);
    const float bo0 = boutp[cl], bo1 = boutp[16 + cl];
#pragma unroll
    for (int r = 0; r < 4; ++r) {
      int n = nb + w * 16 + kg * 4 + r;
      if (n < n_nodes) {
        outp[(size_t)n * OD + cl] = p0[r] + bo0;
        outp[(size_t)n * OD + 16 + cl] = p1[r] + bo1;
      }
    }
  }
}

extern "C" void kernel_launch(void* const* d_in, const int* in_sizes, int n_in,
                              void* d_out, int out_size, void* d_ws, size_t ws_size,
                              hipStream_t stream) {
  const float* x = (const float*)d_in[0];
  const float* h0 = (const float*)d_in[1];
  const float* c0 = (const float*)d_in[2];
  const float* Wxs = (const float*)d_in[3];
  const float* Wxn = (const float*)d_in[4];
  const float* Whs = (const float*)d_in[5];
  const float* Whn = (const float*)d_in[6];
  const float* wc = (const float*)d_in[7];
  const float* bias = (const float*)d_in[8];
  const float* Wout = (const float*)d_in[9];
  const float* bout = (const float*)d_in[10];
  const int* src = (const int*)d_in[11];
  const int* dst = (const int*)d_in[12];

  float* out = (float*)d_out;
  float* outs = out;                                   // [T][N][O]
  float* hstate = out + (size_t)T_STEPS * NN * OD;     // [2][N][64] fp32 (final)
  float* cstate = hstate + (size_t)2 * NN * HD;        // [2][N][64] fp32 (live)

  char* p = (char*)d_ws;
  auto alloc = [&](size_t bytes) {
    char* r = p;
    p += (bytes + 255) & ~(size_t)255;
    return r;
  };
  int* csr = (int*)alloc((size_t)EE * 4);
  uint2* binned = (uint2*)alloc((size_t)EE * 8);
  int* row_ptr = (int*)alloc((size_t)(NN + 1) * 4);
  int* cursor = (int*)alloc((size_t)NN * 4);
  int* deg = (int*)alloc((size_t)NN * 4);
  int* excl = (int*)alloc((size_t)NN * 4);
  int* btot = (int*)alloc(128 * 4);
  int* boffs = (int*)alloc(128 * 4);
  int* bcnt = (int*)alloc(NBK * 4);
  int* bcur = (int*)alloc(NBK * 4);
  float* deg_inv = (float*)alloc((size_t)NN * 4);
  u16* PA = (u16*)alloc((size_t)NN * 128 * 2);    // [x_t | h_l1] bf16
  u16* H0 = (u16*)alloc((size_t)NN * 64 * 2);     // h_l0 bf16
  u16* AGGP = (u16*)alloc((size_t)NN * 128 * 2);  // [agg(x) | agg(h_l1)]
  u16* AGGH = (u16*)alloc((size_t)NN * 64 * 2);   // agg(h_l0) cached across steps
  u16* bprep = (u16*)alloc((size_t)2 * 65536 * 2);
  u16* wprep = (u16*)alloc((size_t)2048 * 2);

  const int nscan = (NN + 1023) / 1024;   // 98
  const int nchunk = (EE + 4095) / 4096;  // 782

  // prologue: bucketed CSR build + weight prep + state init
  hipMemsetAsync(deg, 0, (size_t)NN * 4, stream);
  hipMemsetAsync(bcnt, 0, (size_t)NBK * 4, stream);
  k_bhist<<<nchunk, 256, 0, stream>>>(dst, bcnt, EE);
  k_bscan<<<1, 512, 0, stream>>>(bcnt, bcur);
  k_bscatter<<<nchunk, 256, 0, stream>>>(src, dst, bcur, binned, EE);
  k_count2<<<(EE + 255) / 256, 256, 0, stream>>>(binned, deg, EE);
  k_scanA<<<nscan, 1024, 0, stream>>>(deg, excl, btot, NN);
  k_scanB<<<1, 128, 0, stream>>>(btot, boffs, nscan);
  k_scanC<<<nscan, 1024, 0, stream>>>(deg, excl, boffs, row_ptr, cursor, deg_inv, NN);
  k_scatter2<<<(EE + 255) / 256, 256, 0, stream>>>(binned, cursor, csr, EE);
  k_prep<<<512, 256, 0, stream>>>(Wxs, Wxn, Whs, Whn, bprep);
  k_prepw<<<8, 256, 0, stream>>>(Wout, wprep);
  k_inith<<<NN * 8 / 256, 256, 0, stream>>>(h0, H0, PA);
  hipMemcpyAsync(cstate, c0, (size_t)2 * NN * HD * 4, hipMemcpyDeviceToDevice, stream);
  k_agg_single<<<NN / 4, 256, 0, stream>>>(H0, row_ptr, csr, deg_inv, AGGH);

  for (int t = 0; t < T_STEPS; ++t) {
    int wf = (t == T_STEPS - 1) ? 1 : 0;
    k_convx<<<NN * 8 / 256, 256, 0, stream>>>(x + (size_t)t * NN * HD, PA);
    // dual agg: mean(x_t) and mean(h_l1_old)
    k_agg_pair<<<NN / 4, 256, 0, stream>>>(PA, row_ptr, csr, deg_inv, AGGP);
    // layer 0: inp=x_t(PA,0), xagg=AGGP(0), h=H0 (in-place), hagg=AGGH (cached)
    k_gates<<<(NN + 63) / 64, 256, 0, stream>>>(
        PA, AGGP, H0, AGGH, 128, 128, 64, 64,
        cstate, hstate, bprep, wc, bias,
        wprep, bout, nullptr, NN, wf, 0);
    // agg of new h_l0: layer-1 x-side now AND layer-0 h-side next step
    k_agg_single<<<NN / 4, 256, 0, stream>>>(H0, row_ptr, csr, deg_inv, AGGH);
    // layer 1 (+ fused out-proj): inp=H0, xagg=AGGH, h=PA+64, hagg=AGGP+64
    k_gates<<<(NN + 63) / 64, 256, 0, stream>>>(
        H0, AGGH, PA + 64, AGGP + 64, 64, 64, 128, 128,
        cstate + (size_t)NN * HD, hstate + (size_t)NN * HD,
        bprep + 65536, wc + 192, bias + 256,
        wprep, bout, outs + (size_t)t * NN * OD, NN, wf, 1);
  }
}

// Round 5
// 3139.830 us; speedup vs baseline: 2.3802x; 1.1744x over previous
//
#include <hip/hip_runtime.h>

#define T_STEPS 12
#define NN 100000
#define EE 3200000
#define HD 64
#define OD 32
#define NBK 391  // (NN+255)/256 buckets of 256 nodes

typedef __attribute__((ext_vector_type(8))) short short8;
typedef __attribute__((ext_vector_type(4))) float f32x4;
typedef __attribute__((ext_vector_type(2))) float f32x2;
typedef unsigned short u16;
typedef unsigned char u8;

__device__ __forceinline__ u16 f2b(float x) {
  union { float f; unsigned u; } v; v.f = x;
  unsigned r = v.u + 0x7FFFu + ((v.u >> 16) & 1u);
  return (u16)(r >> 16);
}
__device__ __forceinline__ float b2f(u16 u) {
  union { unsigned u; float f; } v; v.u = ((unsigned)u) << 16;
  return v.f;
}
__device__ __forceinline__ float sigm(float x) {
  x = fminf(fmaxf(x, -30.f), 30.f);
  return 1.0f / (1.0f + __expf(-x));
}
__device__ __forceinline__ float tanh_f(float x) {
  x = fminf(fmaxf(x, -15.f), 15.f);
  float e = __expf(2.0f * x);
  return (e - 1.0f) / (e + 1.0f);
}

// fp8 e4m3 (OCP) pack/unpack via gfx950 HW converts
__device__ __forceinline__ uint2 pack8_fp8(const float* f) {
  unsigned lo = 0, hi = 0;
  lo = __builtin_amdgcn_cvt_pk_fp8_f32(f[0], f[1], lo, false);
  lo = __builtin_amdgcn_cvt_pk_fp8_f32(f[2], f[3], lo, true);
  hi = __builtin_amdgcn_cvt_pk_fp8_f32(f[4], f[5], hi, false);
  hi = __builtin_amdgcn_cvt_pk_fp8_f32(f[6], f[7], hi, true);
  return make_uint2(lo, hi);
}
__device__ __forceinline__ u8 f2q(float x) {
  return (u8)(__builtin_amdgcn_cvt_pk_fp8_f32(x, 0.f, 0u, false) & 0xFFu);
}
__device__ __forceinline__ void acc8_fp8(uint2 v, float* a) {
  f32x2 p0 = __builtin_amdgcn_cvt_pk_f32_fp8(v.x, false);
  f32x2 p1 = __builtin_amdgcn_cvt_pk_f32_fp8(v.x, true);
  f32x2 p2 = __builtin_amdgcn_cvt_pk_f32_fp8(v.y, false);
  f32x2 p3 = __builtin_amdgcn_cvt_pk_f32_fp8(v.y, true);
  a[0] += p0[0]; a[1] += p0[1]; a[2] += p1[0]; a[3] += p1[1];
  a[4] += p2[0]; a[5] += p2[1]; a[6] += p3[0]; a[7] += p3[1];
}

// ================= bucketed CSR build =================
__global__ __launch_bounds__(256) void k_bhist(const int* __restrict__ dst,
                                               int* __restrict__ bcnt, int E) {
  __shared__ int h[NBK];
  for (int i = threadIdx.x; i < NBK; i += 256) h[i] = 0;
  __syncthreads();
  int base = blockIdx.x * 4096;
#pragma unroll
  for (int i = 0; i < 16; ++i) {
    int e = base + i * 256 + threadIdx.x;
    if (e < E) atomicAdd(&h[dst[e] >> 8], 1);
  }
  __syncthreads();
  for (int i = threadIdx.x; i < NBK; i += 256)
    if (h[i]) atomicAdd(&bcnt[i], h[i]);
}

__global__ __launch_bounds__(512) void k_bscan(const int* __restrict__ bcnt,
                                               int* __restrict__ bcur) {
  __shared__ int buf[512];
  int tid = threadIdx.x;
  int v = (tid < NBK) ? bcnt[tid] : 0;
  buf[tid] = v;
  __syncthreads();
  for (int off = 1; off < 512; off <<= 1) {
    int t = (tid >= off) ? buf[tid - off] : 0;
    __syncthreads();
    buf[tid] += t;
    __syncthreads();
  }
  if (tid < NBK) bcur[tid] = buf[tid] - v;
}

__global__ __launch_bounds__(256) void k_bscatter(const int* __restrict__ src,
                                                  const int* __restrict__ dst,
                                                  int* __restrict__ bcur,
                                                  uint2* __restrict__ binned, int E) {
  __shared__ int h[NBK];
  __shared__ int base[NBK];
  __shared__ int cur[NBK];
  for (int i = threadIdx.x; i < NBK; i += 256) { h[i] = 0; cur[i] = 0; }
  __syncthreads();
  int b0 = blockIdx.x * 4096;
  int d[16], s[16];
#pragma unroll
  for (int i = 0; i < 16; ++i) {
    int e = b0 + i * 256 + threadIdx.x;
    if (e < E) {
      d[i] = dst[e];
      s[i] = src[e];
      atomicAdd(&h[d[i] >> 8], 1);
    } else d[i] = -1;
  }
  __syncthreads();
  for (int i = threadIdx.x; i < NBK; i += 256)
    if (h[i]) base[i] = atomicAdd(&bcur[i], h[i]);
  __syncthreads();
#pragma unroll
  for (int i = 0; i < 16; ++i) {
    if (d[i] >= 0) {
      int bk = d[i] >> 8;
      int r = atomicAdd(&cur[bk], 1);
      binned[base[bk] + r] = make_uint2((unsigned)s[i], (unsigned)d[i]);
    }
  }
}

__global__ __launch_bounds__(256) void k_count2(const uint2* __restrict__ binned,
                                                int* __restrict__ deg, int E) {
  int e = blockIdx.x * 256 + threadIdx.x;
  if (e < E) atomicAdd(&deg[binned[e].y], 1);
}

__global__ __launch_bounds__(1024) void k_scanA(const int* __restrict__ deg,
                                                int* __restrict__ excl,
                                                int* __restrict__ btot, int n) {
  __shared__ int buf[1024];
  int tid = threadIdx.x;
  int i = blockIdx.x * 1024 + tid;
  int v = (i < n) ? deg[i] : 0;
  buf[tid] = v;
  __syncthreads();
  for (int off = 1; off < 1024; off <<= 1) {
    int t = (tid >= off) ? buf[tid - off] : 0;
    __syncthreads();
    buf[tid] += t;
    __syncthreads();
  }
  if (i < n) excl[i] = buf[tid] - v;
  if (tid == 1023) btot[blockIdx.x] = buf[1023];
}

__global__ __launch_bounds__(128) void k_scanB(const int* __restrict__ btot,
                                               int* __restrict__ boffs, int nb) {
  __shared__ int buf[128];
  int tid = threadIdx.x;
  int v = (tid < nb) ? btot[tid] : 0;
  buf[tid] = v;
  __syncthreads();
  for (int off = 1; off < 128; off <<= 1) {
    int t = (tid >= off) ? buf[tid - off] : 0;
    __syncthreads();
    buf[tid] += t;
    __syncthreads();
  }
  if (tid < nb) boffs[tid] = buf[tid] - v;
}

__global__ __launch_bounds__(1024) void k_scanC(const int* __restrict__ deg,
                                                const int* __restrict__ excl,
                                                const int* __restrict__ boffs,
                                                int* __restrict__ row_ptr,
                                                int* __restrict__ cursor,
                                                float* __restrict__ deg_inv, int n) {
  int i = blockIdx.x * 1024 + threadIdx.x;
  if (i < n) {
    int v = excl[i] + boffs[blockIdx.x];
    int d = deg[i];
    row_ptr[i] = v;
    cursor[i] = v;
    deg_inv[i] = d ? (1.0f / (float)d) : 0.0f;
    if (i == n - 1) row_ptr[n] = v + d;
  }
}

__global__ __launch_bounds__(256) void k_scatter2(const uint2* __restrict__ binned,
                                                  int* __restrict__ cursor,
                                                  int* __restrict__ csr, int E) {
  int e = blockIdx.x * 256 + threadIdx.x;
  if (e < E) {
    uint2 p = binned[e];
    int pos = atomicAdd(&cursor[p.y], 1);
    csr[pos] = (int)p.x;
  }
}

// ---------------- weight prep: fragment-ordered bf16 B ----------------
__global__ __launch_bounds__(256) void k_prep(const float* __restrict__ Wxs,
                                              const float* __restrict__ Wxn,
                                              const float* __restrict__ Whs,
                                              const float* __restrict__ Whn,
                                              u16* __restrict__ bprep) {
  int idx = blockIdx.x * 256 + threadIdx.x;  // 0..131071
  int l = idx >> 16;
  int kb = (idx >> 13) & 7;
  int fi = (idx >> 9) & 15;
  int ln = (idx >> 3) & 63;
  int j = idx & 7;
  int fc = kb * 32 + ((ln >> 4) << 3) + j;
  int g = fi & 3;
  int kk = ((fi >> 2) << 4) + (ln & 15);
  int t = fc >> 6, f = fc & 63;
  const float* tabs[4] = {Wxs, Wxn, Whs, Whn};
  bprep[idx] = f2b(tabs[t][((size_t)(l * 4 + g) * 64 + f) * 64 + kk]);
}

__global__ __launch_bounds__(256) void k_prepw(const float* __restrict__ Wout,
                                               u16* __restrict__ wp) {
  int idx = blockIdx.x * 256 + threadIdx.x;  // 0..2047
  int kb = idx >> 10;
  int fi = (idx >> 9) & 1;
  int ln = (idx >> 3) & 63;
  int j = idx & 7;
  int k = kb * 32 + ((ln >> 4) << 3) + j;
  int o = fi * 16 + (ln & 15);
  wp[idx] = f2b(Wout[k * 32 + o]);
}

// ---------------- per-step x -> bf16 + fp8 pair buffers ----------------
__global__ __launch_bounds__(256) void k_convx(const float* __restrict__ x,
                                               u16* __restrict__ pa,
                                               u8* __restrict__ paq) {
  int idx = blockIdx.x * 256 + threadIdx.x;  // N*8
  int n = idx >> 3, j = idx & 7;
  float4 v0 = *reinterpret_cast<const float4*>(x + (size_t)n * 64 + j * 8);
  float4 v1 = *reinterpret_cast<const float4*>(x + (size_t)n * 64 + j * 8 + 4);
  float f[8] = {v0.x, v0.y, v0.z, v0.w, v1.x, v1.y, v1.z, v1.w};
  short8 o;
#pragma unroll
  for (int i = 0; i < 8; ++i) o[i] = (short)f2b(f[i]);
  *reinterpret_cast<short8*>(pa + (size_t)n * 128 + j * 8) = o;
  *reinterpret_cast<uint2*>(paq + (size_t)n * 128 + j * 8) = pack8_fp8(f);
}

// ---------------- init h (both layers) -> bf16 + fp8 buffers ----------------
__global__ __launch_bounds__(256) void k_inith(const float* __restrict__ h0,
                                               u16* __restrict__ H0,
                                               u8* __restrict__ H0q,
                                               u16* __restrict__ PA,
                                               u8* __restrict__ PAq) {
  int idx = blockIdx.x * 256 + threadIdx.x;  // N*8
  int n = idx >> 3, j = idx & 7;
#pragma unroll
  for (int L = 0; L < 2; ++L) {
    float4 v0 = *reinterpret_cast<const float4*>(h0 + (size_t)L * NN * 64 + (size_t)n * 64 + j * 8);
    float4 v1 = *reinterpret_cast<const float4*>(h0 + (size_t)L * NN * 64 + (size_t)n * 64 + j * 8 + 4);
    float f[8] = {v0.x, v0.y, v0.z, v0.w, v1.x, v1.y, v1.z, v1.w};
    short8 o;
#pragma unroll
    for (int i = 0; i < 8; ++i) o[i] = (short)f2b(f[i]);
    uint2 q = pack8_fp8(f);
    if (L == 0) {
      *reinterpret_cast<short8*>(H0 + (size_t)n * 64 + j * 8) = o;
      *reinterpret_cast<uint2*>(H0q + (size_t)n * 64 + j * 8) = q;
    } else {
      *reinterpret_cast<short8*>(PA + (size_t)n * 128 + 64 + j * 8) = o;
      *reinterpret_cast<uint2*>(PAq + (size_t)n * 128 + 64 + j * 8) = q;
    }
  }
}

// ---------------- dual mean aggregation over [N][128] fp8 pair ----------------
// 4 edge slots x 16 lanes x 8B; depth-4 main, depth-2/1 tail.
__global__ __launch_bounds__(256) void k_agg_pair(const u8* __restrict__ Q,
                                                  const int* __restrict__ row_ptr,
                                                  const int* __restrict__ csr,
                                                  const float* __restrict__ deg_inv,
                                                  u16* __restrict__ outp) {
  int node = blockIdx.x * 4 + (threadIdx.x >> 6);
  int lane = threadIdx.x & 63;
  int g = lane >> 4, m = lane & 15;
  int start = row_ptr[node], end = row_ptr[node + 1];
  float a[8] = {0, 0, 0, 0, 0, 0, 0, 0};
  int e = start + g;
  for (; e + 12 < end; e += 16) {
    int s0 = csr[e], s1 = csr[e + 4], s2 = csr[e + 8], s3 = csr[e + 12];
    uint2 v0 = *reinterpret_cast<const uint2*>(Q + (size_t)s0 * 128 + m * 8);
    uint2 v1 = *reinterpret_cast<const uint2*>(Q + (size_t)s1 * 128 + m * 8);
    uint2 v2 = *reinterpret_cast<const uint2*>(Q + (size_t)s2 * 128 + m * 8);
    uint2 v3 = *reinterpret_cast<const uint2*>(Q + (size_t)s3 * 128 + m * 8);
    acc8_fp8(v0, a); acc8_fp8(v1, a); acc8_fp8(v2, a); acc8_fp8(v3, a);
  }
  if (e + 4 < end) {
    int s0 = csr[e], s1 = csr[e + 4];
    uint2 v0 = *reinterpret_cast<const uint2*>(Q + (size_t)s0 * 128 + m * 8);
    uint2 v1 = *reinterpret_cast<const uint2*>(Q + (size_t)s1 * 128 + m * 8);
    acc8_fp8(v0, a); acc8_fp8(v1, a);
    e += 8;
  }
  if (e < end) {
    int s0 = csr[e];
    uint2 v0 = *reinterpret_cast<const uint2*>(Q + (size_t)s0 * 128 + m * 8);
    acc8_fp8(v0, a);
  }
#pragma unroll
  for (int off = 16; off < 64; off <<= 1) {
#pragma unroll
    for (int i = 0; i < 8; ++i) a[i] += __shfl_xor(a[i], off);
  }
  if (g == 0) {
    float sc = deg_inv[node];
    short8 o;
#pragma unroll
    for (int i = 0; i < 8; ++i) o[i] = (short)f2b(a[i] * sc);
    *reinterpret_cast<short8*>(outp + (size_t)node * 128 + m * 8) = o;
  }
}

// ---------------- single mean aggregation over [N][64] fp8 ----------------
// 8 edge slots x 8 lanes x 8B; depth-4 main, depth-2/1 tail.
__global__ __launch_bounds__(256) void k_agg_single(const u8* __restrict__ Q,
                                                    const int* __restrict__ row_ptr,
                                                    const int* __restrict__ csr,
                                                    const float* __restrict__ deg_inv,
                                                    u16* __restrict__ outp) {
  int node = blockIdx.x * 4 + (threadIdx.x >> 6);
  int lane = threadIdx.x & 63;
  int g = lane >> 3, m = lane & 7;
  int start = row_ptr[node], end = row_ptr[node + 1];
  float a[8] = {0, 0, 0, 0, 0, 0, 0, 0};
  int e = start + g;
  for (; e + 24 < end; e += 32) {
    int s0 = csr[e], s1 = csr[e + 8], s2 = csr[e + 16], s3 = csr[e + 24];
    uint2 v0 = *reinterpret_cast<const uint2*>(Q + (size_t)s0 * 64 + m * 8);
    uint2 v1 = *reinterpret_cast<const uint2*>(Q + (size_t)s1 * 64 + m * 8);
    uint2 v2 = *reinterpret_cast<const uint2*>(Q + (size_t)s2 * 64 + m * 8);
    uint2 v3 = *reinterpret_cast<const uint2*>(Q + (size_t)s3 * 64 + m * 8);
    acc8_fp8(v0, a); acc8_fp8(v1, a); acc8_fp8(v2, a); acc8_fp8(v3, a);
  }
  if (e + 8 < end) {
    int s0 = csr[e], s1 = csr[e + 8];
    uint2 v0 = *reinterpret_cast<const uint2*>(Q + (size_t)s0 * 64 + m * 8);
    uint2 v1 = *reinterpret_cast<const uint2*>(Q + (size_t)s1 * 64 + m * 8);
    acc8_fp8(v0, a); acc8_fp8(v1, a);
    e += 16;
  }
  if (e < end) {
    int s0 = csr[e];
    uint2 v0 = *reinterpret_cast<const uint2*>(Q + (size_t)s0 * 64 + m * 8);
    acc8_fp8(v0, a);
  }
#pragma unroll
  for (int off = 8; off < 64; off <<= 1) {
#pragma unroll
    for (int i = 0; i < 8; ++i) a[i] += __shfl_xor(a[i], off);
  }
  if (g == 0) {
    float sc = deg_inv[node];
    short8 o;
#pragma unroll
    for (int i = 0; i < 8; ++i) o[i] = (short)f2b(a[i] * sc);
    *reinterpret_cast<short8*>(outp + (size_t)node * 64 + m * 8) = o;
  }
}

// ---------------- fused gate GEMM + LSTM pointwise (+ optional out-proj) ----
__global__ __launch_bounds__(256, 2) void k_gates(
    const u16* __restrict__ tab0, const u16* __restrict__ tab1,
    u16* __restrict__ tab2, const u16* __restrict__ tab3,
    int ld0, int ld1, int ld2, int ld3,
    u8* __restrict__ qtab2, int qld,
    float* __restrict__ cst, float* __restrict__ hf32,
    const u16* __restrict__ bprepl,
    const float* __restrict__ wcl, const float* __restrict__ biasl,
    const u16* __restrict__ wproj, const float* __restrict__ boutp,
    float* __restrict__ outp,
    int n_nodes, int writef32, int doproj) {
  __shared__ u16 Hsm[64 * 64];  // 8 KB, used when doproj
  const int tid = threadIdx.x;
  const int lane = tid & 63;
  const int w = tid >> 6;
  const int nb = blockIdx.x * 64;
  const int cl = lane & 15;
  const int kg = lane >> 4;

  short8 breg[8][4];
#pragma unroll
  for (int kb = 0; kb < 8; ++kb)
#pragma unroll
    for (int fl = 0; fl < 4; ++fl)
      breg[kb][fl] = *reinterpret_cast<const short8*>(
          bprepl + (kb << 13) + (((w << 2) + fl) << 9) + (lane << 3));

  const u16* tabs[4] = {tab0, tab1, tab2, tab3};
  const int lds[4] = {ld0, ld1, ld2, ld3};
  int gnc[4];
#pragma unroll
  for (int rg = 0; rg < 4; ++rg) {
    int g = nb + rg * 16 + cl;
    gnc[rg] = (g < n_nodes) ? g : (n_nodes - 1);
  }

  f32x4 acc[4][4];
  f32x4 z4 = {0.f, 0.f, 0.f, 0.f};
#pragma unroll
  for (int a = 0; a < 4; ++a)
#pragma unroll
    for (int b = 0; b < 4; ++b) acc[a][b] = z4;

  const int koff = kg << 3;
#pragma unroll
  for (int kb = 0; kb < 8; ++kb) {
    const u16* tp = tabs[kb >> 1];
    const int ld = lds[kb >> 1];
    const int idx = ((kb & 1) << 5) + koff;
#pragma unroll
    for (int rg = 0; rg < 4; ++rg) {
      short8 a = *reinterpret_cast<const short8*>(tp + (size_t)gnc[rg] * ld + idx);
      acc[rg][0] = __builtin_amdgcn_mfma_f32_16x16x32_bf16(a, breg[kb][0], acc[rg][0], 0, 0, 0);
      acc[rg][1] = __builtin_amdgcn_mfma_f32_16x16x32_bf16(a, breg[kb][1], acc[rg][1], 0, 0, 0);
      acc[rg][2] = __builtin_amdgcn_mfma_f32_16x16x32_bf16(a, breg[kb][2], acc[rg][2], 0, 0, 0);
      acc[rg][3] = __builtin_amdgcn_mfma_f32_16x16x32_bf16(a, breg[kb][3], acc[rg][3], 0, 0, 0);
    }
  }

  const int k = (w << 4) + cl;
  const float wci = wcl[k], wcf = wcl[64 + k], wco = wcl[128 + k];
  const float bi = biasl[k], bfg = biasl[64 + k], bc = biasl[128 + k], bo = biasl[192 + k];
#pragma unroll
  for (int rg = 0; rg < 4; ++rg) {
#pragma unroll
    for (int r = 0; r < 4; ++r) {
      int n = nb + rg * 16 + kg * 4 + r;
      if (n < n_nodes) {
        size_t off = (size_t)n * 64 + k;
        float c_old = cst[off];
        float ig = sigm(acc[rg][0][r] + wci * c_old + bi);
        float fg = sigm(acc[rg][1][r] + wcf * c_old + bfg);
        float ct = tanh_f(acc[rg][2][r] + bc);
        float nc = fg * c_old + ig * ct;
        float og = sigm(acc[rg][3][r] + wco * nc + bo);
        float nh = og * tanh_f(nc);
        cst[off] = nc;
        u16 hb = f2b(nh);
        tab2[(size_t)n * ld2 + k] = hb;
        qtab2[(size_t)n * qld + k] = f2q(nh);
        if (doproj) Hsm[(rg * 16 + kg * 4 + r) * 64 + k] = hb;
        if (writef32) hf32[off] = nh;
      }
    }
  }

  if (doproj) {
    __syncthreads();
    short8 bw[2][2];
#pragma unroll
    for (int kb = 0; kb < 2; ++kb)
#pragma unroll
      for (int fi = 0; fi < 2; ++fi)
        bw[kb][fi] = *reinterpret_cast<const short8*>(wproj + (((kb * 2 + fi) * 64 + lane) << 3));
    short8 a0 = *reinterpret_cast<const short8*>(&Hsm[(w * 16 + cl) * 64 + kg * 8]);
    short8 a1 = *reinterpret_cast<const short8*>(&Hsm[(w * 16 + cl) * 64 + 32 + kg * 8]);
    f32x4 p0 = z4, p1 = z4;
    p0 = __builtin_amdgcn_mfma_f32_16x16x32_bf16(a0, bw[0][0], p0, 0, 0, 0);
    p0 = __builtin_amdgcn_mfma_f32_16x16x32_bf16(a1, bw[1][0], p0, 0, 0, 0);
    p1 = __builtin_amdgcn_mfma_f32_16x16x32_bf16(a0, bw[0][1], p1, 0, 0, 0);
    p1 = __builtin_amdgcn_mfma_f32_16x16x32_bf16(a1, bw[1][1], p1, 0, 0, 0);
    const float bo0 = boutp[cl], bo1 = boutp[16 + cl];
#pragma unroll
    for (int r = 0; r < 4; ++r) {
      int n = nb + w * 16 + kg * 4 + r;
      if (n < n_nodes) {
        outp[(size_t)n * OD + cl] = p0[r] + bo0;
        outp[(size_t)n * OD + 16 + cl] = p1[r] + bo1;
      }
    }
  }
}

extern "C" void kernel_launch(void* const* d_in, const int* in_sizes, int n_in,
                              void* d_out, int out_size, void* d_ws, size_t ws_size,
                              hipStream_t stream) {
  const float* x = (const float*)d_in[0];
  const float* h0 = (const float*)d_in[1];
  const float* c0 = (const float*)d_in[2];
  const float* Wxs = (const float*)d_in[3];
  const float* Wxn = (const float*)d_in[4];
  const float* Whs = (const float*)d_in[5];
  const float* Whn = (const float*)d_in[6];
  const float* wc = (const float*)d_in[7];
  const float* bias = (const float*)d_in[8];
  const float* Wout = (const float*)d_in[9];
  const float* bout = (const float*)d_in[10];
  const int* src = (const int*)d_in[11];
  const int* dst = (const int*)d_in[12];

  float* out = (float*)d_out;
  float* outs = out;                                   // [T][N][O]
  float* hstate = out + (size_t)T_STEPS * NN * OD;     // [2][N][64] fp32 (final)
  float* cstate = hstate + (size_t)2 * NN * HD;        // [2][N][64] fp32 (live)

  char* p = (char*)d_ws;
  auto alloc = [&](size_t bytes) {
    char* r = p;
    p += (bytes + 255) & ~(size_t)255;
    return r;
  };
  int* csr = (int*)alloc((size_t)EE * 4);
  uint2* binned = (uint2*)alloc((size_t)EE * 8);
  int* row_ptr = (int*)alloc((size_t)(NN + 1) * 4);
  int* cursor = (int*)alloc((size_t)NN * 4);
  int* deg = (int*)alloc((size_t)NN * 4);
  int* excl = (int*)alloc((size_t)NN * 4);
  int* btot = (int*)alloc(128 * 4);
  int* boffs = (int*)alloc(128 * 4);
  int* bcnt = (int*)alloc(NBK * 4);
  int* bcur = (int*)alloc(NBK * 4);
  float* deg_inv = (float*)alloc((size_t)NN * 4);
  u16* PA = (u16*)alloc((size_t)NN * 128 * 2);    // [x_t | h_l1] bf16
  u8* PAq = (u8*)alloc((size_t)NN * 128);         // [x_t | h_l1] fp8 (gather copy)
  u16* H0 = (u16*)alloc((size_t)NN * 64 * 2);     // h_l0 bf16
  u8* H0q = (u8*)alloc((size_t)NN * 64);          // h_l0 fp8 (gather copy)
  u16* AGGP = (u16*)alloc((size_t)NN * 128 * 2);  // [agg(x) | agg(h_l1)] bf16
  u16* AGGH = (u16*)alloc((size_t)NN * 64 * 2);   // agg(h_l0) bf16, cached
  u16* bprep = (u16*)alloc((size_t)2 * 65536 * 2);
  u16* wprep = (u16*)alloc((size_t)2048 * 2);

  const int nscan = (NN + 1023) / 1024;   // 98
  const int nchunk = (EE + 4095) / 4096;  // 782

  // prologue: bucketed CSR build + weight prep + state init
  hipMemsetAsync(deg, 0, (size_t)NN * 4, stream);
  hipMemsetAsync(bcnt, 0, (size_t)NBK * 4, stream);
  k_bhist<<<nchunk, 256, 0, stream>>>(dst, bcnt, EE);
  k_bscan<<<1, 512, 0, stream>>>(bcnt, bcur);
  k_bscatter<<<nchunk, 256, 0, stream>>>(src, dst, bcur, binned, EE);
  k_count2<<<(EE + 255) / 256, 256, 0, stream>>>(binned, deg, EE);
  k_scanA<<<nscan, 1024, 0, stream>>>(deg, excl, btot, NN);
  k_scanB<<<1, 128, 0, stream>>>(btot, boffs, nscan);
  k_scanC<<<nscan, 1024, 0, stream>>>(deg, excl, boffs, row_ptr, cursor, deg_inv, NN);
  k_scatter2<<<(EE + 255) / 256, 256, 0, stream>>>(binned, cursor, csr, EE);
  k_prep<<<512, 256, 0, stream>>>(Wxs, Wxn, Whs, Whn, bprep);
  k_prepw<<<8, 256, 0, stream>>>(Wout, wprep);
  k_inith<<<NN * 8 / 256, 256, 0, stream>>>(h0, H0, H0q, PA, PAq);
  hipMemcpyAsync(cstate, c0, (size_t)2 * NN * HD * 4, hipMemcpyDeviceToDevice, stream);
  k_agg_single<<<NN / 4, 256, 0, stream>>>(H0q, row_ptr, csr, deg_inv, AGGH);

  for (int t = 0; t < T_STEPS; ++t) {
    int wf = (t == T_STEPS - 1) ? 1 : 0;
    k_convx<<<NN * 8 / 256, 256, 0, stream>>>(x + (size_t)t * NN * HD, PA, PAq);
    // dual agg: mean(x_t) and mean(h_l1_old) from fp8 pair
    k_agg_pair<<<NN / 4, 256, 0, stream>>>(PAq, row_ptr, csr, deg_inv, AGGP);
    // layer 0: inp=x_t(PA,0), xagg=AGGP(0), h=H0 (in-place), hagg=AGGH (cached)
    k_gates<<<(NN + 63) / 64, 256, 0, stream>>>(
        PA, AGGP, H0, AGGH, 128, 128, 64, 64,
        H0q, 64,
        cstate, hstate, bprep, wc, bias,
        wprep, bout, nullptr, NN, wf, 0);
    // agg of new h_l0: layer-1 x-side now AND layer-0 h-side next step
    k_agg_single<<<NN / 4, 256, 0, stream>>>(H0q, row_ptr, csr, deg_inv, AGGH);
    // layer 1 (+ fused out-proj): inp=H0, xagg=AGGH, h=PA+64, hagg=AGGP+64
    k_gates<<<(NN + 63) / 64, 256, 0, stream>>>(
        H0, AGGH, PA + 64, AGGP + 64, 64, 64, 128, 128,
        PAq + 64, 128,
        cstate + (size_t)NN * HD, hstate + (size_t)NN * HD,
        bprep + 65536, wc + 192, bias + 256,
        wprep, bout, outs + (size_t)t * NN * OD, NN, wf, 1);
  }
}

// Round 6
// 2998.037 us; speedup vs baseline: 2.4927x; 1.0473x over previous
//
#include <hip/hip_runtime.h>

#define T_STEPS 12
#define NN 100000
#define EE 3200000
#define HD 64
#define OD 32
#define NBK 391  // (NN+255)/256 buckets of 256 nodes

typedef __attribute__((ext_vector_type(8))) short short8;
typedef __attribute__((ext_vector_type(4))) float f32x4;
typedef __attribute__((ext_vector_type(2))) float f32x2;
typedef unsigned short u16;
typedef unsigned char u8;

__device__ __forceinline__ u16 f2b(float x) {
  union { float f; unsigned u; } v; v.f = x;
  unsigned r = v.u + 0x7FFFu + ((v.u >> 16) & 1u);
  return (u16)(r >> 16);
}
__device__ __forceinline__ float sigm(float x) {
  x = fminf(fmaxf(x, -30.f), 30.f);
  return 1.0f / (1.0f + __expf(-x));
}
__device__ __forceinline__ float tanh_f(float x) {
  x = fminf(fmaxf(x, -15.f), 15.f);
  float e = __expf(2.0f * x);
  return (e - 1.0f) / (e + 1.0f);
}

// fp8 e4m3 (OCP) helpers via gfx950 HW converts
__device__ __forceinline__ uint2 pack8_fp8(const float* f) {
  unsigned lo = 0, hi = 0;
  lo = __builtin_amdgcn_cvt_pk_fp8_f32(f[0], f[1], lo, false);
  lo = __builtin_amdgcn_cvt_pk_fp8_f32(f[2], f[3], lo, true);
  hi = __builtin_amdgcn_cvt_pk_fp8_f32(f[4], f[5], hi, false);
  hi = __builtin_amdgcn_cvt_pk_fp8_f32(f[6], f[7], hi, true);
  return make_uint2(lo, hi);
}
__device__ __forceinline__ u8 f2q(float x) {
  return (u8)(__builtin_amdgcn_cvt_pk_fp8_f32(x, 0.f, 0u, false) & 0xFFu);
}
__device__ __forceinline__ void acc8_fp8(uint2 v, float* a) {
  f32x2 p0 = __builtin_amdgcn_cvt_pk_f32_fp8(v.x, false);
  f32x2 p1 = __builtin_amdgcn_cvt_pk_f32_fp8(v.x, true);
  f32x2 p2 = __builtin_amdgcn_cvt_pk_f32_fp8(v.y, false);
  f32x2 p3 = __builtin_amdgcn_cvt_pk_f32_fp8(v.y, true);
  a[0] += p0[0]; a[1] += p0[1]; a[2] += p1[0]; a[3] += p1[1];
  a[4] += p2[0]; a[5] += p2[1]; a[6] += p3[0]; a[7] += p3[1];
}
__device__ __forceinline__ void dec16_acc(uint4 q, float* a) {
  f32x2 t;
  t = __builtin_amdgcn_cvt_pk_f32_fp8(q.x, false); a[0] += t[0]; a[1] += t[1];
  t = __builtin_amdgcn_cvt_pk_f32_fp8(q.x, true);  a[2] += t[0]; a[3] += t[1];
  t = __builtin_amdgcn_cvt_pk_f32_fp8(q.y, false); a[4] += t[0]; a[5] += t[1];
  t = __builtin_amdgcn_cvt_pk_f32_fp8(q.y, true);  a[6] += t[0]; a[7] += t[1];
  t = __builtin_amdgcn_cvt_pk_f32_fp8(q.z, false); a[8] += t[0]; a[9] += t[1];
  t = __builtin_amdgcn_cvt_pk_f32_fp8(q.z, true);  a[10] += t[0]; a[11] += t[1];
  t = __builtin_amdgcn_cvt_pk_f32_fp8(q.w, false); a[12] += t[0]; a[13] += t[1];
  t = __builtin_amdgcn_cvt_pk_f32_fp8(q.w, true);  a[14] += t[0]; a[15] += t[1];
}
__device__ __forceinline__ short8 s8_from_fp8(uint2 q) {
  f32x2 p0 = __builtin_amdgcn_cvt_pk_f32_fp8(q.x, false);
  f32x2 p1 = __builtin_amdgcn_cvt_pk_f32_fp8(q.x, true);
  f32x2 p2 = __builtin_amdgcn_cvt_pk_f32_fp8(q.y, false);
  f32x2 p3 = __builtin_amdgcn_cvt_pk_f32_fp8(q.y, true);
  short8 o;
  o[0] = (short)f2b(p0[0]); o[1] = (short)f2b(p0[1]);
  o[2] = (short)f2b(p1[0]); o[3] = (short)f2b(p1[1]);
  o[4] = (short)f2b(p2[0]); o[5] = (short)f2b(p2[1]);
  o[6] = (short)f2b(p3[0]); o[7] = (short)f2b(p3[1]);
  return o;
}
__device__ __forceinline__ short8 s8_from_f32(float4 a, float4 b) {
  short8 o;
  o[0] = (short)f2b(a.x); o[1] = (short)f2b(a.y);
  o[2] = (short)f2b(a.z); o[3] = (short)f2b(a.w);
  o[4] = (short)f2b(b.x); o[5] = (short)f2b(b.y);
  o[6] = (short)f2b(b.z); o[7] = (short)f2b(b.w);
  return o;
}

// ================= bucketed CSR build =================
__global__ __launch_bounds__(256) void k_bhist(const int* __restrict__ dst,
                                               int* __restrict__ bcnt, int E) {
  __shared__ int h[NBK];
  for (int i = threadIdx.x; i < NBK; i += 256) h[i] = 0;
  __syncthreads();
  int base = blockIdx.x * 4096;
#pragma unroll
  for (int i = 0; i < 16; ++i) {
    int e = base + i * 256 + threadIdx.x;
    if (e < E) atomicAdd(&h[dst[e] >> 8], 1);
  }
  __syncthreads();
  for (int i = threadIdx.x; i < NBK; i += 256)
    if (h[i]) atomicAdd(&bcnt[i], h[i]);
}

__global__ __launch_bounds__(512) void k_bscan(const int* __restrict__ bcnt,
                                               int* __restrict__ bcur) {
  __shared__ int buf[512];
  int tid = threadIdx.x;
  int v = (tid < NBK) ? bcnt[tid] : 0;
  buf[tid] = v;
  __syncthreads();
  for (int off = 1; off < 512; off <<= 1) {
    int t = (tid >= off) ? buf[tid - off] : 0;
    __syncthreads();
    buf[tid] += t;
    __syncthreads();
  }
  if (tid < NBK) bcur[tid] = buf[tid] - v;
}

__global__ __launch_bounds__(256) void k_bscatter(const int* __restrict__ src,
                                                  const int* __restrict__ dst,
                                                  int* __restrict__ bcur,
                                                  uint2* __restrict__ binned, int E) {
  __shared__ int h[NBK];
  __shared__ int base[NBK];
  __shared__ int cur[NBK];
  for (int i = threadIdx.x; i < NBK; i += 256) { h[i] = 0; cur[i] = 0; }
  __syncthreads();
  int b0 = blockIdx.x * 4096;
  int d[16], s[16];
#pragma unroll
  for (int i = 0; i < 16; ++i) {
    int e = b0 + i * 256 + threadIdx.x;
    if (e < E) {
      d[i] = dst[e];
      s[i] = src[e];
      atomicAdd(&h[d[i] >> 8], 1);
    } else d[i] = -1;
  }
  __syncthreads();
  for (int i = threadIdx.x; i < NBK; i += 256)
    if (h[i]) base[i] = atomicAdd(&bcur[i], h[i]);
  __syncthreads();
#pragma unroll
  for (int i = 0; i < 16; ++i) {
    if (d[i] >= 0) {
      int bk = d[i] >> 8;
      int r = atomicAdd(&cur[bk], 1);
      binned[base[bk] + r] = make_uint2((unsigned)s[i], (unsigned)d[i]);
    }
  }
}

__global__ __launch_bounds__(256) void k_count2(const uint2* __restrict__ binned,
                                                int* __restrict__ deg, int E) {
  int e = blockIdx.x * 256 + threadIdx.x;
  if (e < E) atomicAdd(&deg[binned[e].y], 1);
}

__global__ __launch_bounds__(1024) void k_scanA(const int* __restrict__ deg,
                                                int* __restrict__ excl,
                                                int* __restrict__ btot, int n) {
  __shared__ int buf[1024];
  int tid = threadIdx.x;
  int i = blockIdx.x * 1024 + tid;
  int v = (i < n) ? deg[i] : 0;
  buf[tid] = v;
  __syncthreads();
  for (int off = 1; off < 1024; off <<= 1) {
    int t = (tid >= off) ? buf[tid - off] : 0;
    __syncthreads();
    buf[tid] += t;
    __syncthreads();
  }
  if (i < n) excl[i] = buf[tid] - v;
  if (tid == 1023) btot[blockIdx.x] = buf[1023];
}

__global__ __launch_bounds__(128) void k_scanB(const int* __restrict__ btot,
                                               int* __restrict__ boffs, int nb) {
  __shared__ int buf[128];
  int tid = threadIdx.x;
  int v = (tid < nb) ? btot[tid] : 0;
  buf[tid] = v;
  __syncthreads();
  for (int off = 1; off < 128; off <<= 1) {
    int t = (tid >= off) ? buf[tid - off] : 0;
    __syncthreads();
    buf[tid] += t;
    __syncthreads();
  }
  if (tid < nb) boffs[tid] = buf[tid] - v;
}

__global__ __launch_bounds__(1024) void k_scanC(const int* __restrict__ deg,
                                                const int* __restrict__ excl,
                                                const int* __restrict__ boffs,
                                                int* __restrict__ row_ptr,
                                                int* __restrict__ cursor,
                                                float* __restrict__ deg_inv, int n) {
  int i = blockIdx.x * 1024 + threadIdx.x;
  if (i < n) {
    int v = excl[i] + boffs[blockIdx.x];
    int d = deg[i];
    row_ptr[i] = v;
    cursor[i] = v;
    deg_inv[i] = d ? (1.0f / (float)d) : 0.0f;
    if (i == n - 1) row_ptr[n] = v + d;
  }
}

__global__ __launch_bounds__(256) void k_scatter2(const uint2* __restrict__ binned,
                                                  int* __restrict__ cursor,
                                                  int* __restrict__ csr, int E) {
  int e = blockIdx.x * 256 + threadIdx.x;
  if (e < E) {
    uint2 p = binned[e];
    int pos = atomicAdd(&cursor[p.y], 1);
    csr[pos] = (int)p.x;
  }
}

// ---------------- weight prep: fragment-ordered bf16 B ----------------
__global__ __launch_bounds__(256) void k_prep(const float* __restrict__ Wxs,
                                              const float* __restrict__ Wxn,
                                              const float* __restrict__ Whs,
                                              const float* __restrict__ Whn,
                                              u16* __restrict__ bprep) {
  int idx = blockIdx.x * 256 + threadIdx.x;  // 0..131071
  int l = idx >> 16;
  int kb = (idx >> 13) & 7;
  int fi = (idx >> 9) & 15;
  int ln = (idx >> 3) & 63;
  int j = idx & 7;
  int fc = kb * 32 + ((ln >> 4) << 3) + j;
  int g = fi & 3;
  int kk = ((fi >> 2) << 4) + (ln & 15);
  int t = fc >> 6, f = fc & 63;
  const float* tabs[4] = {Wxs, Wxn, Whs, Whn};
  bprep[idx] = f2b(tabs[t][((size_t)(l * 4 + g) * 64 + f) * 64 + kk]);
}

__global__ __launch_bounds__(256) void k_prepw(const float* __restrict__ Wout,
                                               u16* __restrict__ wp) {
  int idx = blockIdx.x * 256 + threadIdx.x;  // 0..2047
  int kb = idx >> 10;
  int fi = (idx >> 9) & 1;
  int ln = (idx >> 3) & 63;
  int j = idx & 7;
  int k = kb * 32 + ((ln >> 4) << 3) + j;
  int o = fi * 16 + (ln & 15);
  wp[idx] = f2b(Wout[k * 32 + o]);
}

// ---------------- batch x -> transposed fp8 XQ[N][T*64] ----------------
__global__ __launch_bounds__(256) void k_convxall(const float* __restrict__ x,
                                                  u8* __restrict__ XQ) {
  int tid = blockIdx.x * 256 + threadIdx.x;  // (t*NN + n)*8 + j
  int j = tid & 7;
  int tn = tid >> 3;
  int n = tn % NN;
  int t = tn / NN;
  const float* rp = x + (size_t)tn * 64 + j * 8;
  float4 v0 = *reinterpret_cast<const float4*>(rp);
  float4 v1 = *reinterpret_cast<const float4*>(rp + 4);
  float f[8] = {v0.x, v0.y, v0.z, v0.w, v1.x, v1.y, v1.z, v1.w};
  *reinterpret_cast<uint2*>(XQ + (size_t)n * 768 + t * 64 + j * 8) = pack8_fp8(f);
}

// ---------------- init h (both layers) -> bf16 tables + fp8 HQ pair ---------
__global__ __launch_bounds__(256) void k_inith(const float* __restrict__ h0,
                                               u16* __restrict__ H0bf,
                                               u16* __restrict__ L1bf,
                                               u8* __restrict__ HQ) {
  int idx = blockIdx.x * 256 + threadIdx.x;  // N*8
  int n = idx >> 3, j = idx & 7;
#pragma unroll
  for (int L = 0; L < 2; ++L) {
    const float* rp = h0 + (size_t)L * NN * 64 + (size_t)n * 64 + j * 8;
    float4 v0 = *reinterpret_cast<const float4*>(rp);
    float4 v1 = *reinterpret_cast<const float4*>(rp + 4);
    float f[8] = {v0.x, v0.y, v0.z, v0.w, v1.x, v1.y, v1.z, v1.w};
    short8 o;
#pragma unroll
    for (int i = 0; i < 8; ++i) o[i] = (short)f2b(f[i]);
    if (L == 0)
      *reinterpret_cast<short8*>(H0bf + (size_t)n * 64 + j * 8) = o;
    else
      *reinterpret_cast<short8*>(L1bf + (size_t)n * 64 + j * 8) = o;
    *reinterpret_cast<uint2*>(HQ + (size_t)n * 128 + L * 64 + j * 8) = pack8_fp8(f);
  }
}

// ---------------- batched x aggregation: all T steps in one pass ------------
// 4 edge slots (g) x 16 lanes (m); per edge 3 passes of 16B/lane (768 B total).
// lane m, pass p covers t = p*4 + (m>>2), f0 = (m&3)*16.
__global__ __launch_bounds__(256) void k_aggx(const u8* __restrict__ XQ,
                                              const int* __restrict__ row_ptr,
                                              const int* __restrict__ csr,
                                              const float* __restrict__ deg_inv,
                                              u8* __restrict__ AGGXq) {
  int node = blockIdx.x * 4 + (threadIdx.x >> 6);
  int lane = threadIdx.x & 63;
  int g = lane >> 4, m = lane & 15;
  int start = row_ptr[node], end = row_ptr[node + 1];
  float acc[3][16];
#pragma unroll
  for (int p = 0; p < 3; ++p)
#pragma unroll
    for (int i = 0; i < 16; ++i) acc[p][i] = 0.f;
  int e = start + g;
  for (; e + 4 < end; e += 8) {
    int s0 = csr[e], s1 = csr[e + 4];
    const u8* r0 = XQ + (size_t)s0 * 768 + m * 16;
    const u8* r1 = XQ + (size_t)s1 * 768 + m * 16;
#pragma unroll
    for (int p = 0; p < 3; ++p) {
      uint4 q0 = *reinterpret_cast<const uint4*>(r0 + p * 256);
      uint4 q1 = *reinterpret_cast<const uint4*>(r1 + p * 256);
      dec16_acc(q0, acc[p]);
      dec16_acc(q1, acc[p]);
    }
  }
  if (e < end) {
    int s0 = csr[e];
    const u8* r0 = XQ + (size_t)s0 * 768 + m * 16;
#pragma unroll
    for (int p = 0; p < 3; ++p) {
      uint4 q0 = *reinterpret_cast<const uint4*>(r0 + p * 256);
      dec16_acc(q0, acc[p]);
    }
  }
#pragma unroll
  for (int off = 16; off < 64; off <<= 1)
#pragma unroll
    for (int p = 0; p < 3; ++p)
#pragma unroll
      for (int i = 0; i < 16; ++i) acc[p][i] += __shfl_xor(acc[p][i], off);
  if (g == 0) {
    float sc = deg_inv[node];
#pragma unroll
    for (int p = 0; p < 3; ++p) {
      float f[16];
#pragma unroll
      for (int i = 0; i < 16; ++i) f[i] = acc[p][i] * sc;
      uint4 o;
      unsigned w;
      w = 0; w = __builtin_amdgcn_cvt_pk_fp8_f32(f[0], f[1], w, false);
      w = __builtin_amdgcn_cvt_pk_fp8_f32(f[2], f[3], w, true); o.x = w;
      w = 0; w = __builtin_amdgcn_cvt_pk_fp8_f32(f[4], f[5], w, false);
      w = __builtin_amdgcn_cvt_pk_fp8_f32(f[6], f[7], w, true); o.y = w;
      w = 0; w = __builtin_amdgcn_cvt_pk_fp8_f32(f[8], f[9], w, false);
      w = __builtin_amdgcn_cvt_pk_fp8_f32(f[10], f[11], w, true); o.z = w;
      w = 0; w = __builtin_amdgcn_cvt_pk_fp8_f32(f[12], f[13], w, false);
      w = __builtin_amdgcn_cvt_pk_fp8_f32(f[14], f[15], w, true); o.w = w;
      int t = p * 4 + (m >> 2);
      *reinterpret_cast<uint4*>(AGGXq + ((size_t)t * NN + node) * 64 + (m & 3) * 16) = o;
    }
  }
}

// ---------------- dual mean aggregation over HQ [N][128] fp8 ----------------
__global__ __launch_bounds__(256) void k_agg_pair(const u8* __restrict__ Q,
                                                  const int* __restrict__ row_ptr,
                                                  const int* __restrict__ csr,
                                                  const float* __restrict__ deg_inv,
                                                  u16* __restrict__ outp) {
  int node = blockIdx.x * 4 + (threadIdx.x >> 6);
  int lane = threadIdx.x & 63;
  int g = lane >> 4, m = lane & 15;
  int start = row_ptr[node], end = row_ptr[node + 1];
  float a[8] = {0, 0, 0, 0, 0, 0, 0, 0};
  int e = start + g;
  for (; e + 12 < end; e += 16) {
    int s0 = csr[e], s1 = csr[e + 4], s2 = csr[e + 8], s3 = csr[e + 12];
    uint2 v0 = *reinterpret_cast<const uint2*>(Q + (size_t)s0 * 128 + m * 8);
    uint2 v1 = *reinterpret_cast<const uint2*>(Q + (size_t)s1 * 128 + m * 8);
    uint2 v2 = *reinterpret_cast<const uint2*>(Q + (size_t)s2 * 128 + m * 8);
    uint2 v3 = *reinterpret_cast<const uint2*>(Q + (size_t)s3 * 128 + m * 8);
    acc8_fp8(v0, a); acc8_fp8(v1, a); acc8_fp8(v2, a); acc8_fp8(v3, a);
  }
  if (e + 4 < end) {
    int s0 = csr[e], s1 = csr[e + 4];
    uint2 v0 = *reinterpret_cast<const uint2*>(Q + (size_t)s0 * 128 + m * 8);
    uint2 v1 = *reinterpret_cast<const uint2*>(Q + (size_t)s1 * 128 + m * 8);
    acc8_fp8(v0, a); acc8_fp8(v1, a);
    e += 8;
  }
  if (e < end) {
    int s0 = csr[e];
    uint2 v0 = *reinterpret_cast<const uint2*>(Q + (size_t)s0 * 128 + m * 8);
    acc8_fp8(v0, a);
  }
#pragma unroll
  for (int off = 16; off < 64; off <<= 1) {
#pragma unroll
    for (int i = 0; i < 8; ++i) a[i] += __shfl_xor(a[i], off);
  }
  if (g == 0) {
    float sc = deg_inv[node];
    short8 o;
#pragma unroll
    for (int i = 0; i < 8; ++i) o[i] = (short)f2b(a[i] * sc);
    *reinterpret_cast<short8*>(outp + (size_t)node * 128 + m * 8) = o;
  }
}

// ---------------- layer-0 gates: A = {x fp32, AGGX fp8, H0 bf16, AGGHL bf16}
__global__ __launch_bounds__(256, 2) void k_gates0(
    const float* __restrict__ xin, const u8* __restrict__ aggxq,
    u16* __restrict__ h0bf, const u16* __restrict__ agghl,
    u8* __restrict__ hq, float* __restrict__ cst, float* __restrict__ hf32,
    const u16* __restrict__ bprepl,
    const float* __restrict__ wcl, const float* __restrict__ biasl,
    int n_nodes, int writef32) {
  const int tid = threadIdx.x;
  const int lane = tid & 63;
  const int w = tid >> 6;
  const int nb = blockIdx.x * 64;
  const int cl = lane & 15;
  const int kg = lane >> 4;

  short8 breg[8][4];
#pragma unroll
  for (int kb = 0; kb < 8; ++kb)
#pragma unroll
    for (int fl = 0; fl < 4; ++fl)
      breg[kb][fl] = *reinterpret_cast<const short8*>(
          bprepl + (kb << 13) + (((w << 2) + fl) << 9) + (lane << 3));

  int gnc[4];
#pragma unroll
  for (int rg = 0; rg < 4; ++rg) {
    int g = nb + rg * 16 + cl;
    gnc[rg] = (g < n_nodes) ? g : (n_nodes - 1);
  }

  f32x4 acc[4][4];
  f32x4 z4 = {0.f, 0.f, 0.f, 0.f};
#pragma unroll
  for (int a = 0; a < 4; ++a)
#pragma unroll
    for (int b = 0; b < 4; ++b) acc[a][b] = z4;

  const int koff = kg << 3;
#pragma unroll
  for (int kb = 0; kb < 8; ++kb) {
    const int idx = ((kb & 1) << 5) + koff;
#pragma unroll
    for (int rg = 0; rg < 4; ++rg) {
      short8 a;
      if (kb < 2) {
        const float* rp = xin + (size_t)gnc[rg] * 64 + idx;
        a = s8_from_f32(*reinterpret_cast<const float4*>(rp),
                        *reinterpret_cast<const float4*>(rp + 4));
      } else if (kb < 4) {
        a = s8_from_fp8(*reinterpret_cast<const uint2*>(aggxq + (size_t)gnc[rg] * 64 + idx));
      } else if (kb < 6) {
        a = *reinterpret_cast<const short8*>(h0bf + (size_t)gnc[rg] * 64 + idx);
      } else {
        a = *reinterpret_cast<const short8*>(agghl + (size_t)gnc[rg] * 128 + idx);
      }
      acc[rg][0] = __builtin_amdgcn_mfma_f32_16x16x32_bf16(a, breg[kb][0], acc[rg][0], 0, 0, 0);
      acc[rg][1] = __builtin_amdgcn_mfma_f32_16x16x32_bf16(a, breg[kb][1], acc[rg][1], 0, 0, 0);
      acc[rg][2] = __builtin_amdgcn_mfma_f32_16x16x32_bf16(a, breg[kb][2], acc[rg][2], 0, 0, 0);
      acc[rg][3] = __builtin_amdgcn_mfma_f32_16x16x32_bf16(a, breg[kb][3], acc[rg][3], 0, 0, 0);
    }
  }

  const int k = (w << 4) + cl;
  const float wci = wcl[k], wcf = wcl[64 + k], wco = wcl[128 + k];
  const float bi = biasl[k], bfg = biasl[64 + k], bc = biasl[128 + k], bo = biasl[192 + k];
#pragma unroll
  for (int rg = 0; rg < 4; ++rg) {
#pragma unroll
    for (int r = 0; r < 4; ++r) {
      int n = nb + rg * 16 + kg * 4 + r;
      if (n < n_nodes) {
        size_t off = (size_t)n * 64 + k;
        float c_old = cst[off];
        float ig = sigm(acc[rg][0][r] + wci * c_old + bi);
        float fg = sigm(acc[rg][1][r] + wcf * c_old + bfg);
        float ct = tanh_f(acc[rg][2][r] + bc);
        float nc = fg * c_old + ig * ct;
        float og = sigm(acc[rg][3][r] + wco * nc + bo);
        float nh = og * tanh_f(nc);
        cst[off] = nc;
        h0bf[off] = f2b(nh);
        hq[(size_t)n * 128 + k] = f2q(nh);
        if (writef32) hf32[off] = nh;
      }
    }
  }
}

// ---------------- layer-1 gates + fused out-proj: all-bf16 A ----------------
__global__ __launch_bounds__(256, 2) void k_gates1(
    const u16* __restrict__ h0bf, const u16* __restrict__ agghl,
    u16* __restrict__ l1bf, u8* __restrict__ hq,
    float* __restrict__ cst, float* __restrict__ hf32,
    const u16* __restrict__ bprepl,
    const float* __restrict__ wcl, const float* __restrict__ biasl,
    const u16* __restrict__ wproj, const float* __restrict__ boutp,
    float* __restrict__ outp, int n_nodes, int writef32) {
  __shared__ u16 Hsm[64 * 64];  // 8 KB
  const int tid = threadIdx.x;
  const int lane = tid & 63;
  const int w = tid >> 6;
  const int nb = blockIdx.x * 64;
  const int cl = lane & 15;
  const int kg = lane >> 4;

  short8 breg[8][4];
#pragma unroll
  for (int kb = 0; kb < 8; ++kb)
#pragma unroll
    for (int fl = 0; fl < 4; ++fl)
      breg[kb][fl] = *reinterpret_cast<const short8*>(
          bprepl + (kb << 13) + (((w << 2) + fl) << 9) + (lane << 3));

  int gnc[4];
#pragma unroll
  for (int rg = 0; rg < 4; ++rg) {
    int g = nb + rg * 16 + cl;
    gnc[rg] = (g < n_nodes) ? g : (n_nodes - 1);
  }

  f32x4 acc[4][4];
  f32x4 z4 = {0.f, 0.f, 0.f, 0.f};
#pragma unroll
  for (int a = 0; a < 4; ++a)
#pragma unroll
    for (int b = 0; b < 4; ++b) acc[a][b] = z4;

  const int koff = kg << 3;
#pragma unroll
  for (int kb = 0; kb < 8; ++kb) {
    const int idx = ((kb & 1) << 5) + koff;
#pragma unroll
    for (int rg = 0; rg < 4; ++rg) {
      short8 a;
      if (kb < 2) {
        a = *reinterpret_cast<const short8*>(h0bf + (size_t)gnc[rg] * 64 + idx);
      } else if (kb < 4) {
        a = *reinterpret_cast<const short8*>(agghl + (size_t)gnc[rg] * 128 + idx);
      } else if (kb < 6) {
        a = *reinterpret_cast<const short8*>(l1bf + (size_t)gnc[rg] * 64 + idx);
      } else {
        a = *reinterpret_cast<const short8*>(agghl + (size_t)gnc[rg] * 128 + 64 + idx);
      }
      acc[rg][0] = __builtin_amdgcn_mfma_f32_16x16x32_bf16(a, breg[kb][0], acc[rg][0], 0, 0, 0);
      acc[rg][1] = __builtin_amdgcn_mfma_f32_16x16x32_bf16(a, breg[kb][1], acc[rg][1], 0, 0, 0);
      acc[rg][2] = __builtin_amdgcn_mfma_f32_16x16x32_bf16(a, breg[kb][2], acc[rg][2], 0, 0, 0);
      acc[rg][3] = __builtin_amdgcn_mfma_f32_16x16x32_bf16(a, breg[kb][3], acc[rg][3], 0, 0, 0);
    }
  }

  const int k = (w << 4) + cl;
  const float wci = wcl[k], wcf = wcl[64 + k], wco = wcl[128 + k];
  const float bi = biasl[k], bfg = biasl[64 + k], bc = biasl[128 + k], bo = biasl[192 + k];
#pragma unroll
  for (int rg = 0; rg < 4; ++rg) {
#pragma unroll
    for (int r = 0; r < 4; ++r) {
      int n = nb + rg * 16 + kg * 4 + r;
      if (n < n_nodes) {
        size_t off = (size_t)n * 64 + k;
        float c_old = cst[off];
        float ig = sigm(acc[rg][0][r] + wci * c_old + bi);
        float fg = sigm(acc[rg][1][r] + wcf * c_old + bfg);
        float ct = tanh_f(acc[rg][2][r] + bc);
        float nc = fg * c_old + ig * ct;
        float og = sigm(acc[rg][3][r] + wco * nc + bo);
        float nh = og * tanh_f(nc);
        cst[off] = nc;
        u16 hb = f2b(nh);
        l1bf[off] = hb;
        hq[(size_t)n * 128 + 64 + k] = f2q(nh);
        Hsm[(rg * 16 + kg * 4 + r) * 64 + k] = hb;
        if (writef32) hf32[off] = nh;
      }
    }
  }

  __syncthreads();
  short8 bw[2][2];
#pragma unroll
  for (int kb = 0; kb < 2; ++kb)
#pragma unroll
    for (int fi = 0; fi < 2; ++fi)
      bw[kb][fi] = *reinterpret_cast<const short8*>(wproj + (((kb * 2 + fi) * 64 + lane) << 3));
  short8 a0 = *reinterpret_cast<const short8*>(&Hsm[(w * 16 + cl) * 64 + kg * 8]);
  short8 a1 = *reinterpret_cast<const short8*>(&Hsm[(w * 16 + cl) * 64 + 32 + kg * 8]);
  f32x4 p0 = z4, p1 = z4;
  p0 = __builtin_amdgcn_mfma_f32_16x16x32_bf16(a0, bw[0][0], p0, 0, 0, 0);
  p0 = __builtin_amdgcn_mfma_f32_16x16x32_bf16(a1, bw[1][0], p0, 0, 0, 0);
  p1 = __builtin_amdgcn_mfma_f32_16x16x32_bf16(a0, bw[0][1], p1, 0, 0, 0);
  p1 = __builtin_amdgcn_mfma_f32_16x16x32_bf16(a1, bw[1][1], p1, 0, 0, 0);
  const float bo0 = boutp[cl], bo1 = boutp[16 + cl];
#pragma unroll
  for (int r = 0; r < 4; ++r) {
    int n = nb + w * 16 + kg * 4 + r;
    if (n < n_nodes) {
      outp[(size_t)n * OD + cl] = p0[r] + bo0;
      outp[(size_t)n * OD + 16 + cl] = p1[r] + bo1;
    }
  }
}

extern "C" void kernel_launch(void* const* d_in, const int* in_sizes, int n_in,
                              void* d_out, int out_size, void* d_ws, size_t ws_size,
                              hipStream_t stream) {
  const float* x = (const float*)d_in[0];
  const float* h0 = (const float*)d_in[1];
  const float* c0 = (const float*)d_in[2];
  const float* Wxs = (const float*)d_in[3];
  const float* Wxn = (const float*)d_in[4];
  const float* Whs = (const float*)d_in[5];
  const float* Whn = (const float*)d_in[6];
  const float* wc = (const float*)d_in[7];
  const float* bias = (const float*)d_in[8];
  const float* Wout = (const float*)d_in[9];
  const float* bout = (const float*)d_in[10];
  const int* src = (const int*)d_in[11];
  const int* dst = (const int*)d_in[12];

  float* out = (float*)d_out;
  float* outs = out;                                   // [T][N][O]
  float* hstate = out + (size_t)T_STEPS * NN * OD;     // [2][N][64] fp32 (final)
  float* cstate = hstate + (size_t)2 * NN * HD;        // [2][N][64] fp32 (live)

  char* p = (char*)d_ws;
  auto alloc = [&](size_t bytes) {
    char* r = p;
    p += (bytes + 255) & ~(size_t)255;
    return r;
  };
  int* csr = (int*)alloc((size_t)EE * 4);
  u8* XQ = (u8*)alloc((size_t)NN * 768);        // x fp8, node-major [N][T*64]
  uint2* binned = (uint2*)XQ;                   // alias: binned dead before XQ written
  u8* AGGXq = (u8*)alloc((size_t)T_STEPS * NN * 64);  // [T][N][64] fp8
  int* row_ptr = (int*)alloc((size_t)(NN + 1) * 4);
  int* cursor = (int*)alloc((size_t)NN * 4);
  int* deg = (int*)alloc((size_t)NN * 4);
  int* excl = (int*)alloc((size_t)NN * 4);
  int* btot = (int*)alloc(128 * 4);
  int* boffs = (int*)alloc(128 * 4);
  int* bcnt = (int*)alloc(NBK * 4);
  int* bcur = (int*)alloc(NBK * 4);
  float* deg_inv = (float*)alloc((size_t)NN * 4);
  u16* H0bf = (u16*)alloc((size_t)NN * 64 * 2);   // h_l0 bf16
  u16* L1bf = (u16*)alloc((size_t)NN * 64 * 2);   // h_l1 bf16
  u8* HQ = (u8*)alloc((size_t)NN * 128);          // [h_l0 | h_l1] fp8 pair
  u16* AGGHL = (u16*)alloc((size_t)NN * 128 * 2); // [agg(h_l0) | agg(h_l1)] bf16
  u16* bprep = (u16*)alloc((size_t)2 * 65536 * 2);
  u16* wprep = (u16*)alloc((size_t)2048 * 2);

  const int nscan = (NN + 1023) / 1024;   // 98
  const int nchunk = (EE + 4095) / 4096;  // 782

  // prologue: bucketed CSR build
  hipMemsetAsync(deg, 0, (size_t)NN * 4, stream);
  hipMemsetAsync(bcnt, 0, (size_t)NBK * 4, stream);
  k_bhist<<<nchunk, 256, 0, stream>>>(dst, bcnt, EE);
  k_bscan<<<1, 512, 0, stream>>>(bcnt, bcur);
  k_bscatter<<<nchunk, 256, 0, stream>>>(src, dst, bcur, binned, EE);
  k_count2<<<(EE + 255) / 256, 256, 0, stream>>>(binned, deg, EE);
  k_scanA<<<nscan, 1024, 0, stream>>>(deg, excl, btot, NN);
  k_scanB<<<1, 128, 0, stream>>>(btot, boffs, nscan);
  k_scanC<<<nscan, 1024, 0, stream>>>(deg, excl, boffs, row_ptr, cursor, deg_inv, NN);
  k_scatter2<<<(EE + 255) / 256, 256, 0, stream>>>(binned, cursor, csr, EE);
  // weight prep + state init + batched x processing (XQ overwrites binned)
  k_prep<<<512, 256, 0, stream>>>(Wxs, Wxn, Whs, Whn, bprep);
  k_prepw<<<8, 256, 0, stream>>>(Wout, wprep);
  k_convxall<<<(T_STEPS * NN * 8 + 255) / 256, 256, 0, stream>>>(x, XQ);
  k_inith<<<NN * 8 / 256, 256, 0, stream>>>(h0, H0bf, L1bf, HQ);
  hipMemcpyAsync(cstate, c0, (size_t)2 * NN * HD * 4, hipMemcpyDeviceToDevice, stream);
  k_aggx<<<(NN + 3) / 4, 256, 0, stream>>>(XQ, row_ptr, csr, deg_inv, AGGXq);
  k_agg_pair<<<(NN + 3) / 4, 256, 0, stream>>>(HQ, row_ptr, csr, deg_inv, AGGHL);

  for (int t = 0; t < T_STEPS; ++t) {
    int wf = (t == T_STEPS - 1) ? 1 : 0;
    // layer 0: inp=x_t fp32, xagg=AGGXq[t] fp8, h=H0bf, hagg=AGGHL[:,0:64]
    k_gates0<<<(NN + 63) / 64, 256, 0, stream>>>(
        x + (size_t)t * NN * HD, AGGXq + (size_t)t * NN * 64,
        H0bf, AGGHL, HQ, cstate, hstate, bprep, wc, bias, NN, wf);
    // one pair gather: agg(h_l0_new) -> AGGHL[:,0:64], agg(h_l1_old) -> AGGHL[:,64:]
    k_agg_pair<<<(NN + 3) / 4, 256, 0, stream>>>(HQ, row_ptr, csr, deg_inv, AGGHL);
    // layer 1 (+ out-proj): inp=H0_new, xagg=AGGHL[:,0:64], h=L1bf, hagg=AGGHL[:,64:]
    k_gates1<<<(NN + 63) / 64, 256, 0, stream>>>(
        H0bf, AGGHL, L1bf, HQ,
        cstate + (size_t)NN * HD, hstate + (size_t)NN * HD,
        bprep + 65536, wc + 192, bias + 256,
        wprep, bout, outs + (size_t)t * NN * OD, NN, wf);
  }
}